// Round 16
// baseline (5689.340 us; speedup 1.0000x reference)
//
#include <hip/hip_runtime.h>
#include <hip/hip_bf16.h>

#define Bsz 32
#define Tn  64
#define Vn  32000
#define En  300
#define Hn  512
#define NFn 128
#define Dn  32
#define G4  2048
#define LIN 332
#define NWG 256

// workspace offsets (float units)
#define OFF_MPROJ 0
#define OFF_E0    (OFF_MPROJ + 131072)     /* fp32 [64][4 bg][2048][8] */
#define OFF_PG0B  (OFF_E0 + 4194304)       /* legacy scratch (unused now) */
#define OFF_H1T   (OFF_PG0B + 65536)
#define OFF_H2T0  (OFF_H1T + 16384)
#define OFF_H2T1  (OFF_H2T0 + 16384)
#define OFF_H2BB  (OFF_H2T1 + 16384)
#define OFF_C1T   (OFF_H2BB + 16384)
#define OFF_C2T   (OFF_C1T + 16384)
#define OFF_FLG   (OFF_C2T + 16384)        /* 16 ctr x 64 slots x 4 floats */
#define OFF_DONE  (OFF_FLG + 4096)         /* 16 x 16 floats */
#define OFF_VC    (OFF_DONE + 256)
#define OFF_MKEY  (OFF_VC + 16)            /* fp32 [32][128][512] */
#define OFF_WHT   (OFF_MKEY + 2097152)     /* unused */
#define OFF_WCTX  (OFF_WHT + 262144)       /* fp32 [2048][32] */
#define OFF_X     (OFF_WCTX + 65536)       /* fp32 [2048][320]; HBF reuses after p2c */
#define OFF_W0    (OFF_X + 655360)         /* fp32 [2048][320] */
#define OFF_HBF   OFF_X                    /* bf16 [2048][512] */
#define OFF_FCWBF (OFF_X + 524288)         /* bf16 [32000][512] -> 8192000 floats */

// step-unique buffers in the LOGITS region of d_out (each slot written before
// read every call; fc_gemm fully overwrites logits afterwards)
#define O_H1S  0              /* fp32 [64][4][512][8]  */
#define O_H2S  1048576        /* fp32 [65][4][512][8]  */
#define O_QS   2113536        /* fp32 [64][32][512]    */
#define O_CTXP 3162112        /* fp32 [64][32][8][32]  */
#define O_DENP 3686400        /* fp32 [64][32][8]      */
#define O_ES   3702784        /* fp32 [64][32][128]    */

// output offsets (float units)
#define OUT_HF  65536000
#define OUT_CF  65568768
#define OUT_ATT 65601536

// scan LDS map (floats)
#define L_HS2   0        /* [8][512] */
#define L_HS1   4096     /* [8][512] */
#define L_GL    8192     /* [32][9]  */
#define L_PG0   8480     /* [32][8]  */
#define L_C1    8736     /* [64]     */
#define L_C2    8800     /* [64]     */
#define L_CTX   8864     /* [8][33]  */
#define L_DEN   9128     /* [8]      */
#define L_QL    9136     /* [528]    */
#define L_VL    9664     /* [528]    */
#define L_SP    10192    /* [16][17] */
#define L_ESL   10464    /* [16]     */
#define L_CP    10480    /* [32][17] */
#define L_W0    11024    /* [32][512] whh0 WG rows, resident all 64 steps */
#define SCAN_LDS_FLOATS 27408
#define SCAN_LDS_BYTES  (SCAN_LDS_FLOATS*4)

typedef __attribute__((ext_vector_type(8))) short short8;
typedef __attribute__((ext_vector_type(4))) float f32x4;
typedef unsigned short u16;

__device__ __forceinline__ float frcp(float x){ return __builtin_amdgcn_rcpf(x); }
__device__ __forceinline__ float ftanh(float x){
  float e = __expf(2.0f*x);
  return 1.0f - 2.0f*frcp(e+1.0f);
}
__device__ __forceinline__ float fsig(float x){
  return frcp(1.0f + __expf(-x));
}
__device__ __forceinline__ u16 f2bf(float f){
  __hip_bfloat16 h = __float2bfloat16(f);
  u16 r; __builtin_memcpy(&r, &h, 2); return r;
}

// ---- coherent (write-through) access for flags + cross-WG producer stores ----
__device__ __forceinline__ float ldc1(const float* p){
  return __hip_atomic_load(p, __ATOMIC_RELAXED, __HIP_MEMORY_SCOPE_AGENT);
}
__device__ __forceinline__ void stc1(float* p, float v){
  __hip_atomic_store(p, v, __ATOMIC_RELAXED, __HIP_MEMORY_SCOPE_AGENT);
}

// ---- flag/aggregator barrier: BUSY-WAIT (no s_sleep — wake-latency probe) ----
__device__ __forceinline__ void flag_store(float* ws, int c, int slot, float v){
  stc1(ws + OFF_FLG + c*256 + slot*4, v);
}
__device__ __forceinline__ void aggregate(float* ws, int c, float tgt, int tid){
  if (tid < 64){
    const float* fl = ws + OFF_FLG + c*256;
    unsigned cc = 0;
    while (true){
      float v = ldc1(fl + tid*4);
      if (__ballot(v >= tgt) == ~0ull) break;
      if (++cc >= (1u<<22)) break;   // terminate rather than hang
    }
    if (tid == 0) stc1(ws + OFF_DONE + c*16, tgt);
  }
}
__device__ __forceinline__ void waitD(float* ws, int c, float tgt){
  __syncthreads();
  if (threadIdx.x == 0){
    unsigned cc = 0;
    while (ldc1(ws + OFF_DONE + c*16) < tgt){
      if (++cc >= (1u<<24)) break;   // terminate rather than hang
    }
  }
  __syncthreads();
  asm volatile("" ::: "memory");
}

// 32-value reduce-scatter over 64 lanes; owner slot = bitrev5(L&31) for L<32.
__device__ __forceinline__ float redux32(float (&v)[32], int L){
  #pragma unroll
  for (int i=0;i<5;i++){
    const int m = 1<<i, h = 16>>i;
    const bool up = (L & m);
    #pragma unroll
    for (int u=0; u<h; u++){
      float send = up ? v[u] : v[u+h];
      float keep = up ? v[u+h] : v[u];
      v[u] = keep + __shfl_xor(send, m, 64);
    }
  }
  v[0] += __shfl_xor(v[0], 32, 64);
  return v[0];
}
// 16-value version: slot = bitrev4(L&15) for L<16
__device__ __forceinline__ float redux16(float (&v)[16], int L){
  #pragma unroll
  for (int i=0;i<4;i++){
    const int m = 1<<i, h = 8>>i;
    const bool up = (L & m);
    #pragma unroll
    for (int u=0; u<h; u++){
      float send = up ? v[u] : v[u+h];
      float keep = up ? v[u+h] : v[u];
      v[u] = keep + __shfl_xor(send, m, 64);
    }
  }
  v[0] += __shfl_xor(v[0], 16, 64);
  v[0] += __shfl_xor(v[0], 32, 64);
  return v[0];
}

// ---------------- P1: midi_proj (f32) + midi_key (f32) ----------------
__global__ __launch_bounds__(1024) void p1_midi(
    const float* __restrict__ midi, const float* __restrict__ mp_w,
    const float* __restrict__ mp_b, const float* __restrict__ wm,
    float* __restrict__ ws)
{
  __shared__ float ms[NFn*Dn];
  __shared__ float pj[NFn*33];
  __shared__ float mpw[Dn*33];
  __shared__ float mpb[Dn];
  int b = blockIdx.x, tid = threadIdx.x;
  for (int i=tid;i<NFn*Dn;i+=1024) ms[i] = midi[b*NFn*Dn + i];
  { int e = tid>>5, d = tid&31; mpw[e*33+d] = mp_w[tid]; }
  if (tid < Dn) mpb[tid] = mp_b[tid];
  __syncthreads();
  float* mproj = ws + OFF_MPROJ;
  for (int i=tid;i<NFn*Dn;i+=1024){
    int f = i>>5, e = i&31;
    float a = mpb[e];
    #pragma unroll
    for (int d=0;d<Dn;d++) a += ms[f*32+d]*mpw[e*33+d];
    a = fmaxf(a, 0.0f);
    pj[f*33+e] = a;
    mproj[b*NFn*Dn + i] = a;
  }
  __syncthreads();
  int h = tid & 511, fh = tid >> 9;
  float wreg[32];
  #pragma unroll
  for (int d=0;d<32;d++) wreg[d] = wm[h*32+d];
  float* mkf = ws + OFF_MKEY + b*(NFn*Hn);
  for (int ff=0; ff<64; ff++){
    int f = fh*64 + ff;
    float a = 0.f;
    #pragma unroll
    for (int d=0;d<32;d++) a += pj[f*33+d]*wreg[d];
    mkf[f*512 + h] = a;
  }
}

// ---------------- P2a: gather embeddings -> f32 X[2048][320] ----------------
__global__ __launch_bounds__(256) void p2a_x(
    const int* __restrict__ seq, const float* __restrict__ emb,
    float* __restrict__ ws)
{
  int idx = blockIdx.x*256 + threadIdx.x;
  int bt = idx / 80, c4 = idx - bt*80;
  int b = bt & 31, t = bt >> 5;
  float4 x = {0.f,0.f,0.f,0.f};
  if (c4 < 75){
    int s = seq[b*Tn + t];
    x = *(const float4*)(emb + (long)s*En + c4*4);
  }
  *(float4*)(ws + OFF_X + bt*320 + c4*4) = x;
}

// ---------------- P2b: wih0[:, :300] -> f32 [2048][320] padded ----------------
__global__ __launch_bounds__(256) void p2b_w(
    const float* __restrict__ wih0, float* __restrict__ ws)
{
  int idx = blockIdx.x*256 + threadIdx.x;
  int j = idx / 80, c4 = idx - j*80;
  float4 x = {0.f,0.f,0.f,0.f};
  if (c4 < 75) x = *(const float4*)(wih0 + (long)j*LIN + c4*4);
  *(float4*)(ws + OFF_W0 + j*320 + c4*4) = x;
}

// ---------------- P2c: E0 = W0 @ X^T + bias (fp32 SGEMM 128x128x32) ----------------
// E0 layout: [t][bg(4)][2048 rows][8 b]
__global__ __launch_bounds__(256) void p2c_e0(
    const float* __restrict__ ws_c, const float* __restrict__ bih0,
    const float* __restrict__ bhh0, float* __restrict__ ws)
{
  const float* A  = ws_c + OFF_W0;
  const float* Bm = ws_c + OFF_X;
  __shared__ float Al[32][132];
  __shared__ float Bl[32][132];
  int tid = threadIdx.x;
  int j0t = blockIdx.x*128, bt0 = blockIdx.y*128;
  int tx = tid & 15, ty = tid >> 4;
  float acc[8][8];
  #pragma unroll
  for (int i=0;i<8;i++)
    #pragma unroll
    for (int j=0;j<8;j++) acc[i][j] = 0.f;

  int m = tid >> 1;
  int kq = (tid & 1) * 16;
  for (int kk=0; kk<320; kk+=32){
    __syncthreads();
    {
      const float* As = A  + (long)(j0t+m)*320 + kk + kq;
      const float* Bs = Bm + (long)(bt0+m)*320 + kk + kq;
      float4 a0 = *(const float4*)(As+0), a1 = *(const float4*)(As+4);
      float4 a2 = *(const float4*)(As+8), a3 = *(const float4*)(As+12);
      float4 b0 = *(const float4*)(Bs+0), b1 = *(const float4*)(Bs+4);
      float4 b2 = *(const float4*)(Bs+8), b3 = *(const float4*)(Bs+12);
      Al[kq+0][m]=a0.x; Al[kq+1][m]=a0.y; Al[kq+2][m]=a0.z; Al[kq+3][m]=a0.w;
      Al[kq+4][m]=a1.x; Al[kq+5][m]=a1.y; Al[kq+6][m]=a1.z; Al[kq+7][m]=a1.w;
      Al[kq+8][m]=a2.x; Al[kq+9][m]=a2.y; Al[kq+10][m]=a2.z; Al[kq+11][m]=a2.w;
      Al[kq+12][m]=a3.x; Al[kq+13][m]=a3.y; Al[kq+14][m]=a3.z; Al[kq+15][m]=a3.w;
      Bl[kq+0][m]=b0.x; Bl[kq+1][m]=b0.y; Bl[kq+2][m]=b0.z; Bl[kq+3][m]=b0.w;
      Bl[kq+4][m]=b1.x; Bl[kq+5][m]=b1.y; Bl[kq+6][m]=b1.z; Bl[kq+7][m]=b1.w;
      Bl[kq+8][m]=b2.x; Bl[kq+9][m]=b2.y; Bl[kq+10][m]=b2.z; Bl[kq+11][m]=b2.w;
      Bl[kq+12][m]=b3.x; Bl[kq+13][m]=b3.y; Bl[kq+14][m]=b3.z; Bl[kq+15][m]=b3.w;
    }
    __syncthreads();
    #pragma unroll 4
    for (int k=0;k<32;k++){
      float4 a0 = *(const float4*)&Al[k][ty*8];
      float4 a1 = *(const float4*)&Al[k][ty*8+4];
      float4 b0 = *(const float4*)&Bl[k][tx*8];
      float4 b1 = *(const float4*)&Bl[k][tx*8+4];
      float av[8] = {a0.x,a0.y,a0.z,a0.w,a1.x,a1.y,a1.z,a1.w};
      float bv[8] = {b0.x,b0.y,b0.z,b0.w,b1.x,b1.y,b1.z,b1.w};
      #pragma unroll
      for (int i=0;i<8;i++)
        #pragma unroll
        for (int j=0;j<8;j++) acc[i][j] += av[i]*bv[j];
    }
  }
  float* E0 = ws + OFF_E0;
  #pragma unroll
  for (int i=0;i<8;i++){
    int j = j0t + ty*8 + i;
    float be = bih0[j] + bhh0[j];
    #pragma unroll
    for (int jj=0;jj<8;jj++){
      int c = bt0 + tx*8 + jj;
      int tt = c >> 5, bb = c & 31;
      E0[tt*65536 + (bb>>3)*16384 + j*8 + (bb&7)] = acc[i][jj] + be;
    }
  }
}

// ---------------- P3: fc_w -> bf16 ----------------
__global__ __launch_bounds__(256) void p3_cvt(
    const float* __restrict__ fcw, float* __restrict__ ws)
{
  u16* dst = (u16*)(ws + OFF_FCWBF);
  int base = (blockIdx.x*256 + threadIdx.x)*8;
  float4 x = *(const float4*)(fcw+base);
  float4 y = *(const float4*)(fcw+base+4);
  short8 p;
  p[0]=(short)f2bf(x.x); p[1]=(short)f2bf(x.y); p[2]=(short)f2bf(x.z); p[3]=(short)f2bf(x.w);
  p[4]=(short)f2bf(y.x); p[5]=(short)f2bf(y.y); p[6]=(short)f2bf(y.z); p[7]=(short)f2bf(y.w);
  *(short8*)(dst+base) = p;
}

// ---------------- P5: wih0[:,300:332] -> f32 [2048][32] ----------------
__global__ __launch_bounds__(256) void p5_wctx(
    const float* __restrict__ wih0, float* __restrict__ ws)
{
  int idx = blockIdx.x*256 + threadIdx.x;
  int j = idx >> 5, d = idx & 31;
  ws[OFF_WCTX + idx] = wih0[(long)j*LIN + En + d];
}

// ---------------- P6: C = sum |v| ----------------
__global__ __launch_bounds__(512) void p6_vc(
    const float* __restrict__ v, float* __restrict__ ws)
{
  __shared__ float s[8];
  int tid = threadIdx.x;
  float a = fabsf(v[tid]);
  #pragma unroll
  for (int m=1;m<64;m<<=1) a += __shfl_xor(a, m, 64);
  if ((tid&63)==0) s[tid>>6] = a;
  __syncthreads();
  if (tid==0){
    float c=0;
    #pragma unroll
    for (int i=0;i<8;i++) c += s[i];
    ws[OFF_VC] = c;
  }
}

// ---------------- P0: zero H2S slot 0 (in out) + flags (in ws) ----------------
__global__ __launch_bounds__(256) void p0_init(float* __restrict__ ws,
                                               float* __restrict__ out){
  int idx = blockIdx.x*256 + threadIdx.x;   // grid 64 -> 16384
  out[O_H2S + idx] = 0.f;
  if (idx < 4352) ws[OFF_FLG + idx] = 0.f;  // FLG[16][64][4] + DONE[16][16]
}

// ---------------- fused 64-step scan: 256 WGs x 256 thr (1 wave/SIMD) ----------------
__global__ __launch_bounds__(256, 1)
void scan_all(
    const float* __restrict__ wih1, const float* __restrict__ whh1,
    const float* __restrict__ whh0, const float* __restrict__ bih1,
    const float* __restrict__ bhh1, const float* __restrict__ wh,
    const float* __restrict__ vvec, float* __restrict__ ws,
    float* __restrict__ out)
{
  extern __shared__ float lds[];
  float* hs2  = lds + L_HS2;    // [8 b][512 k]  h2(t-1)
  float* hs1  = lds + L_HS1;    // [8 b][512 k]  h1(t)
  float* gl   = lds + L_GL;     // [32][9]
  float* pg0l = lds + L_PG0;    // [32][8]
  float* c1l  = lds + L_C1;     // [64]
  float* c2l  = lds + L_C2;     // [64]
  float* ctxl = lds + L_CTX;    // [8][33]
  float* denl = lds + L_DEN;    // [8]
  float* ql   = lds + L_QL;     // [528] padded
  float* vl   = lds + L_VL;     // [528]
  float* sp   = lds + L_SP;     // [16][17]
  float* esl  = lds + L_ESL;    // [16]
  float* cp   = lds + L_CP;     // [32][17]
  float* w0l  = lds + L_W0;     // [32][512] whh0 rows (persist 64 steps)

  const int wg = blockIdx.x, tid = threadIdx.x;
  const int rg = wg >> 2, bg = wg & 3;          // P1/P3/P4 identity
  const int b2 = wg >> 3, fs = wg & 7;          // P2 identity (batch b2, f-slice fs)
  const int bgp = wg >> 6;
  const int wv = tid >> 6, L = tid & 63;
  u16* hbf = (u16*)(ws + OFF_HBF);

  // ---- persistent per-lane weights: wih1/whh1, 128 VGPR, loaded once ----
  float w_a[8][8], w_b[8][8];
  #pragma unroll
  for (int r=0;r<8;r++){
    int row = wv*512 + rg*8 + r;
    #pragma unroll
    for (int j=0;j<8;j++){
      w_a[r][j] = wih1[(long)row*512 + j*64 + L];
      w_b[r][j] = whh1[(long)row*512 + j*64 + L];
    }
  }
  // ---- whh0 WG rows -> LDS, loaded once ----
  for (int c=0; c<64; c++){
    int idx = c*256 + tid;          // 0..16383
    int lr = idx >> 9, k = idx & 511;
    int grow = (lr>>3)*512 + rg*8 + (lr&7);
    w0l[idx] = whh0[(long)grow*512 + k];
  }

  // lane redux constants
  const int s4 = ((L&1)<<3) | ((L&2)<<1) | ((L&4)>>1) | ((L&8)>>3);
  const int q_sr = s4 >> 3, q_sx = s4 & 7;                       // redux16 owner (L<16)
  const int s5 = ((L&1)<<4) | ((L&2)<<2) | (L&4) | ((L&8)>>2) | ((L&16)>>4);
  const int r_sr = s5 >> 3, r_sx = s5 & 7;                       // redux32 owner (L<32)
  float bsum[2]; int glIdx[2], pgIdx[2];
  #pragma unroll
  for (int p=0;p<2;p++){
    int kk = p*4 + r_sr;
    int row = wv*512 + rg*8 + kk;
    bsum[p] = bih1[row] + bhh1[row];
    glIdx[p] = (wv*8 + kk)*9 + r_sx;
    pgIdx[p] = (wv*8 + kk)*8 + r_sx;
  }

  // ---- persistent LDS init ----
  if (tid < 64){ c1l[tid] = 0.f; c2l[tid] = 0.f; }
  {
    int r = tid>>3, bb = tid&7;
    int row = ((r>>3)<<9) + rg*8 + (r&7);
    pg0l[r*8+bb] = ws[OFF_E0 + bg*16384 + row*8 + bb];   // pg0(0) = E0[0]
  }
  vl[tid + (tid>>5)] = vvec[tid];
  { int t2 = tid + 256; vl[t2 + (t2>>5)] = vvec[t2]; }
  const float Cv = ws[OFF_VC];
  __syncthreads();

  for (int t=0; t<64; t++){
    const float tgt = (float)(t+1);
    // ================= P1: q = wh @ h2(t-1) =================
    if (t > 0) waitD(ws, 0+bg, (float)t);
    {
      const float* h2b = out + O_H2S + t*16384 + bg*4096;
      float4 v0 = *(const float4*)(h2b +    0 + tid*4);
      float4 v1 = *(const float4*)(h2b + 1024 + tid*4);
      float4 v2 = *(const float4*)(h2b + 2048 + tid*4);
      float4 v3 = *(const float4*)(h2b + 3072 + tid*4);
      int kb = tid >> 1, bb0 = (tid&1)*4;
      hs2[(bb0+0)*512 +   0 + kb] = v0.x; hs2[(bb0+1)*512 +   0 + kb] = v0.y;
      hs2[(bb0+2)*512 +   0 + kb] = v0.z; hs2[(bb0+3)*512 +   0 + kb] = v0.w;
      hs2[(bb0+0)*512 + 128 + kb] = v1.x; hs2[(bb0+1)*512 + 128 + kb] = v1.y;
      hs2[(bb0+2)*512 + 128 + kb] = v1.z; hs2[(bb0+3)*512 + 128 + kb] = v1.w;
      hs2[(bb0+0)*512 + 256 + kb] = v2.x; hs2[(bb0+1)*512 + 256 + kb] = v2.y;
      hs2[(bb0+2)*512 + 256 + kb] = v2.z; hs2[(bb0+3)*512 + 256 + kb] = v2.w;
      hs2[(bb0+0)*512 + 384 + kb] = v3.x; hs2[(bb0+1)*512 + 384 + kb] = v3.y;
      hs2[(bb0+2)*512 + 384 + kb] = v3.z; hs2[(bb0+3)*512 + 384 + kb] = v3.w;
    }
    __syncthreads();
    {
      const float* w0p = wh + (long)(rg*8 + wv*2)*512;   // L2-resident WG rows
      const float* w1p = w0p + 512;
      float vq[16];
      #pragma unroll
      for (int i=0;i<16;i++) vq[i] = 0.f;
      #pragma unroll
      for (int j=0;j<8;j++){
        int k = j*64 + L;
        float wa = w0p[k], wb = w1p[k];
        #pragma unroll
        for (int x=0;x<8;x++){
          float hv = hs2[x*512+k];
          vq[x] += wa*hv; vq[8+x] += wb*hv;
        }
      }
      float qv = redux16(vq, L);
      if (L < 16)
        stc1(out + O_QS + t*16384 + (bg*8+q_sx)*512 + rg*8 + wv*2 + q_sr, qv);
    }
    __syncthreads();
    if (tid == 0) flag_store(ws, 4+bg, wg>>2, tgt);
    if (wg < 4) aggregate(ws, 4+wg, tgt, tid);

    // ================= P2: scores / exp / ctx-partials =================
    waitD(ws, 4+bgp, tgt);
    ql[tid + (tid>>5)] = out[O_QS + t*16384 + b2*512 + tid];
    { int t2 = tid + 256; ql[t2 + (t2>>5)] = out[O_QS + t*16384 + b2*512 + t2]; }
    __syncthreads();
    {
      int f = tid>>4, hg = tid&15;
      const float* mkr = ws + OFF_MKEY + b2*65536 + (fs*16+f)*512 + hg*32;
      const float* qb = ql + hg*33;
      const float* vb = vl + hg*33;
      float s = 0.f;
      #pragma unroll
      for (int c=0; c<32; c+=4){
        float4 m4 = *(const float4*)(mkr+c);
        s += vb[c+0]*ftanh(qb[c+0]+m4.x) + vb[c+1]*ftanh(qb[c+1]+m4.y)
           + vb[c+2]*ftanh(qb[c+2]+m4.z) + vb[c+3]*ftanh(qb[c+3]+m4.w);
      }
      sp[f*17+hg] = s;
    }
    __syncthreads();
    if (tid < 16){
      float s = 0.f;
      #pragma unroll
      for (int g=0; g<16; g++) s += sp[tid*17+g];
      float e = __expf(s - Cv);
      esl[tid] = e;
      stc1(out + O_ES + t*4096 + b2*128 + fs*16 + tid, e);
    }
    __syncthreads();
    if (tid == 0){
      float d = 0.f;
      #pragma unroll
      for (int i=0;i<16;i++) d += esl[i];
      stc1(out + O_DENP + t*256 + b2*8 + fs, d);
    }
    {
      int d2 = tid&31, f0 = tid>>5;
      cp[d2*17+f0]   = esl[f0]  * ws[OFF_MPROJ + b2*4096 + (fs*16+f0)*32   + d2];
      cp[d2*17+f0+8] = esl[f0+8]* ws[OFF_MPROJ + b2*4096 + (fs*16+f0+8)*32 + d2];
    }
    __syncthreads();
    if (tid < 32){
      float s = 0.f;
      #pragma unroll
      for (int ff=0; ff<16; ff++) s += cp[tid*17+ff];
      stc1(out + O_CTXP + t*8192 + b2*256 + fs*32 + tid, s);
    }
    __syncthreads();
    if (tid == 0) flag_store(ws, 8+bgp, wg&63, tgt);
    if ((wg&63) == 0) aggregate(ws, 8+bgp, tgt, tid);

    // ================= P3: ctx gather + gates0 + cell1 =================
    waitD(ws, 8+bg, tgt);
    if (tid < 8){
      float dsum = 0.f;
      #pragma unroll
      for (int f2=0; f2<8; f2++) dsum += out[O_DENP + t*256 + (bg*8+tid)*8 + f2];
      denl[tid] = frcp(dsum);
    }
    __syncthreads();
    {
      int bb = tid>>5, d = tid&31;
      float s = 0.f;
      #pragma unroll
      for (int f2=0; f2<8; f2++) s += out[O_CTXP + t*8192 + (bg*8+bb)*256 + f2*32 + d];
      ctxl[bb*33+d] = s * denl[bb];
    }
    if (rg == 0){
      #pragma unroll
      for (int i0=0; i0<4; i0++){
        int i = tid + i0*256;
        int bb = i>>7, f = i&127;
        float e = out[O_ES + t*4096 + (bg*8+bb)*128 + f];
        __builtin_nontemporal_store(e * denl[bb],
            out + OUT_ATT + (bg*8+bb)*8192 + t*128 + f);
      }
    }
    __syncthreads();
    {
      int r = tid>>3, bb = tid&7;
      int row = ((r>>3)<<9) + rg*8 + (r&7);
      float g0 = pg0l[r*8+bb];
      const float* wr = ws + OFF_WCTX + row*32;
      #pragma unroll
      for (int d2=0; d2<32; d2+=4){
        float4 w4 = *(const float4*)(wr+d2);
        g0 += w4.x*ctxl[bb*33+d2] + w4.y*ctxl[bb*33+d2+1]
            + w4.z*ctxl[bb*33+d2+2] + w4.w*ctxl[bb*33+d2+3];
      }
      gl[r*9+bb] = g0;
    }
    __syncthreads();
    if (tid < 64){
      int kk = tid>>3, bb = tid&7;
      float gi = gl[(kk)*9+bb],     gf = gl[(8+kk)*9+bb];
      float gg2 = gl[(16+kk)*9+bb], go = gl[(24+kk)*9+bb];
      float cp2 = c1l[tid];
      float cn = fsig(gf)*cp2 + fsig(gi)*ftanh(gg2);
      float hn = fsig(go)*ftanh(cn);
      c1l[tid] = cn;
      stc1(out + O_H1S + t*16384 + bg*4096 + (rg*8+kk)*8 + bb, hn);
      if (t == 63){
        int bgl = bg*8+bb, kgl = rg*8+kk;
        __builtin_nontemporal_store(hn, out + OUT_HF + bgl*512 + kgl);
        __builtin_nontemporal_store(cn, out + OUT_CF + bgl*512 + kgl);
      }
    }
    __syncthreads();
    if (tid == 0) flag_store(ws, 12+bg, wg>>2, tgt);
    if (wg < 4) aggregate(ws, 12+wg, tgt, tid);

    // ================= P4: gates1 + cell2 (+ pg0(t+1) off critical path) ======
    waitD(ws, 12+bg, tgt);
    {
      const float* h1b = out + O_H1S + t*16384 + bg*4096;
      float4 v0 = *(const float4*)(h1b +    0 + tid*4);
      float4 v1 = *(const float4*)(h1b + 1024 + tid*4);
      float4 v2 = *(const float4*)(h1b + 2048 + tid*4);
      float4 v3 = *(const float4*)(h1b + 3072 + tid*4);
      int kb = tid >> 1, bb0 = (tid&1)*4;
      hs1[(bb0+0)*512 +   0 + kb] = v0.x; hs1[(bb0+1)*512 +   0 + kb] = v0.y;
      hs1[(bb0+2)*512 +   0 + kb] = v0.z; hs1[(bb0+3)*512 +   0 + kb] = v0.w;
      hs1[(bb0+0)*512 + 128 + kb] = v1.x; hs1[(bb0+1)*512 + 128 + kb] = v1.y;
      hs1[(bb0+2)*512 + 128 + kb] = v1.z; hs1[(bb0+3)*512 + 128 + kb] = v1.w;
      hs1[(bb0+0)*512 + 256 + kb] = v2.x; hs1[(bb0+1)*512 + 256 + kb] = v2.y;
      hs1[(bb0+2)*512 + 256 + kb] = v2.z; hs1[(bb0+3)*512 + 256 + kb] = v2.w;
      hs1[(bb0+0)*512 + 384 + kb] = v3.x; hs1[(bb0+1)*512 + 384 + kb] = v3.y;
      hs1[(bb0+2)*512 + 384 + kb] = v3.z; hs1[(bb0+3)*512 + 384 + kb] = v3.w;
    }
    __syncthreads();
    // gates1 = wih1 @ h1 + whh1 @ h2(t-1): two passes of 4 rows x 8 b
    #pragma unroll
    for (int p=0; p<2; p++){
      float vals[32];
      #pragma unroll
      for (int i=0;i<32;i++) vals[i] = 0.f;
      #pragma unroll
      for (int j=0;j<8;j++){
        int k = j*64 + L;
        float h1v[8], h2v[8];
        #pragma unroll
        for (int x=0;x<8;x++){ h1v[x] = hs1[x*512+k]; h2v[x] = hs2[x*512+k]; }
        #pragma unroll
        for (int r=0;r<4;r++){
          const float wa = w_a[p*4+r][j], wb = w_b[p*4+r][j];
          #pragma unroll
          for (int x=0;x<8;x++) vals[r*8+x] += wa*h1v[x] + wb*h2v[x];
        }
      }
      float v0 = redux32(vals, L);
      if (L < 32) gl[glIdx[p]] = v0 + bsum[p];
    }
    __syncthreads();
    if (tid < 64){
      int kk = tid>>3, bb = tid&7;
      float gi = gl[(kk)*9+bb],     gf = gl[(8+kk)*9+bb];
      float gg2 = gl[(16+kk)*9+bb], go = gl[(24+kk)*9+bb];
      float cp3 = c2l[tid];
      float cn = fsig(gf)*cp3 + fsig(gi)*ftanh(gg2);
      float hn = fsig(go)*ftanh(cn);
      c2l[tid] = cn;
      int k2 = rg*8+kk, b = bg*8+bb;
      stc1(out + O_H2S + (t+1)*16384 + bg*4096 + k2*8 + bb, hn);
      __builtin_nontemporal_store(f2bf(hn), hbf + (t*32+b)*512 + k2);
      if (t == 63){
        __builtin_nontemporal_store(hn, out + OUT_HF + 16384 + b*512 + k2);
        __builtin_nontemporal_store(cn, out + OUT_CF + 16384 + b*512 + k2);
      }
    }
    __syncthreads();                 // drains h2 stores before signal
    if (tid == 0) flag_store(ws, 0+bg, wg>>2, tgt);
    if (wg < 4) aggregate(ws, 0+wg, tgt, tid);

    // pg0(t+1) = whh0 @ h1 (+ E0[t+1]) — whh0 in LDS, WG-local consumer
    if (t < 63){
      #pragma unroll
      for (int p=0; p<2; p++){
        float vals[32];
        #pragma unroll
        for (int i=0;i<32;i++) vals[i] = 0.f;
        #pragma unroll
        for (int j=0;j<8;j++){
          int k = j*64 + L;
          float h1v[8];
          #pragma unroll
          for (int x=0;x<8;x++) h1v[x] = hs1[x*512+k];
          #pragma unroll
          for (int r=0;r<4;r++){
            const float wc = w0l[(wv*8 + p*4 + r)*512 + k];
            #pragma unroll
            for (int x=0;x<8;x++) vals[r*8+x] += wc*h1v[x];
          }
        }
        float v0 = redux32(vals, L);
        if (L < 32) pg0l[pgIdx[p]] = v0;
      }
      __syncthreads();
      {
        int r = tid>>3, bb = tid&7;
        int row = ((r>>3)<<9) + rg*8 + (r&7);
        pg0l[r*8+bb] += ws[OFF_E0 + (t+1)*65536 + bg*16384 + row*8 + bb];
      }
    }
    // loop-top waitD's __syncthreads orders pg0l for next P3
  }
}

// ---------------- FC: logits = h @ fc_w^T + fc_b (bf16 MFMA) ----------------
__global__ __launch_bounds__(256) void fc_gemm(
    const float* __restrict__ ws_f, const float* __restrict__ fcb,
    float* __restrict__ out)
{
  const u16* A  = (const u16*)(ws_f + OFF_FCWBF);
  const u16* Bm = (const u16*)(ws_f + OFF_HBF);
  __shared__ u16 Al[128*40];
  __shared__ u16 Bl[128*40];
  int tid = threadIdx.x;
  int v0 = blockIdx.x*128, bt0 = blockIdx.y*128;
  int lane = tid & 63, wv = tid >> 6;
  int wr = wv >> 1, wc = wv & 1;
  f32x4 acc[4][4];
  #pragma unroll
  for (int i=0;i<4;i++)
    #pragma unroll
    for (int j=0;j<4;j++) acc[i][j] = (f32x4){0.f,0.f,0.f,0.f};

  int ar = wr*64 + (lane&15);
  int br = wc*64 + (lane&15);
  int ks = (lane>>4)*8;

  for (int kk=0; kk<512; kk+=32){
    __syncthreads();
    #pragma unroll
    for (int i=0;i<2;i++){
      int ld = tid + 256*i;
      int row = ld >> 2, cs = (ld & 3)*8;
      *(int4*)(&Al[row*40+cs]) = *(const int4*)(A  + (v0+row)*512 + kk + cs);
      *(int4*)(&Bl[row*40+cs]) = *(const int4*)(Bm + (bt0+row)*512 + kk + cs);
    }
    __syncthreads();
    short8 af[4], bf[4];
    #pragma unroll
    for (int m=0;m<4;m++) af[m] = *(const short8*)(&Al[(ar+m*16)*40 + ks]);
    #pragma unroll
    for (int n=0;n<4;n++) bf[n] = *(const short8*)(&Bl[(br+n*16)*40 + ks]);
    #pragma unroll
    for (int m=0;m<4;m++)
      #pragma unroll
      for (int n=0;n<4;n++)
        acc[m][n] = __builtin_amdgcn_mfma_f32_16x16x32_bf16(af[m], bf[n], acc[m][n], 0,0,0);
  }
  int r4 = (lane>>4)*4;
  #pragma unroll
  for (int m=0;m<4;m++){
    int v = v0 + wr*64 + m*16 + r4;
    float4 bias = *(const float4*)(fcb + v);
    #pragma unroll
    for (int n=0;n<4;n++){
      int bt = bt0 + wc*64 + n*16 + (lane&15);
      int b = bt & 31, t = bt >> 5;
      f32x4 a = acc[m][n];
      float4 res = { a[0]+bias.x, a[1]+bias.y, a[2]+bias.z, a[3]+bias.w };
      *(float4*)(out + b*2048000 + t*32000 + v) = res;
    }
  }
}

extern "C" void kernel_launch(void* const* d_in, const int* in_sizes, int n_in,
                              void* d_out, int out_size, void* d_ws, size_t ws_size,
                              hipStream_t stream)
{
  const int*   seq  = (const int*)d_in[0];
  const float* midi = (const float*)d_in[1];
  const float* emb  = (const float*)d_in[2];
  const float* mpw  = (const float*)d_in[3];
  const float* mpb  = (const float*)d_in[4];
  const float* wh   = (const float*)d_in[5];
  const float* wm   = (const float*)d_in[6];
  const float* vv   = (const float*)d_in[7];
  const float* wih0 = (const float*)d_in[8];
  const float* whh0 = (const float*)d_in[9];
  const float* bih0 = (const float*)d_in[10];
  const float* bhh0 = (const float*)d_in[11];
  const float* wih1 = (const float*)d_in[12];
  const float* whh1 = (const float*)d_in[13];
  const float* bih1 = (const float*)d_in[14];
  const float* bhh1 = (const float*)d_in[15];
  const float* fcw  = (const float*)d_in[16];
  const float* fcb  = (const float*)d_in[17];
  float* out = (float*)d_out;
  float* ws  = (float*)d_ws;

  // allow >64KB dynamic LDS for the scan (host-side, capture-safe)
  hipFuncSetAttribute((const void*)scan_all,
                      hipFuncAttributeMaxDynamicSharedMemorySize,
                      SCAN_LDS_BYTES);

  p1_midi<<<32, 1024, 0, stream>>>(midi, mpw, mpb, wm, ws);
  p2a_x  <<<640, 256, 0, stream>>>(seq, emb, ws);
  p2b_w  <<<640, 256, 0, stream>>>(wih0, ws);
  p2c_e0 <<<dim3(16,16), 256, 0, stream>>>(ws, bih0, bhh0, ws);
  p3_cvt <<<8000, 256, 0, stream>>>(fcw, ws);
  p5_wctx<<<256, 256, 0, stream>>>(wih0, ws);
  p6_vc  <<<1, 512, 0, stream>>>(vv, ws);
  p0_init<<<64, 256, 0, stream>>>(ws, out);

  scan_all<<<NWG, 256, SCAN_LDS_BYTES, stream>>>(wih1, whh1, whh0, bih1, bhh1,
                                                 wh, vv, ws, out);

  fc_gemm<<<dim3(250,16), 256, 0, stream>>>(ws, fcb, out);
}

// Round 17
// 5566.132 us; speedup vs baseline: 1.0221x; 1.0221x over previous
//
#include <hip/hip_runtime.h>
#include <hip/hip_bf16.h>

#define Bsz 32
#define Tn  64
#define Vn  32000
#define En  300
#define Hn  512
#define NFn 128
#define Dn  32
#define G4  2048
#define LIN 332
#define NWG 256

// workspace offsets (float units)
#define OFF_MPROJ 0
#define OFF_E0    (OFF_MPROJ + 131072)     /* fp32 [64][4 bg][2048][8] */
#define OFF_PG0B  (OFF_E0 + 4194304)       /* legacy scratch (unused now) */
#define OFF_H1T   (OFF_PG0B + 65536)
#define OFF_H2T0  (OFF_H1T + 16384)
#define OFF_H2T1  (OFF_H2T0 + 16384)
#define OFF_H2BB  (OFF_H2T1 + 16384)
#define OFF_C1T   (OFF_H2BB + 16384)
#define OFF_C2T   (OFF_C1T + 16384)
#define OFF_FLG   (OFF_C2T + 16384)        /* 16 ctr x 64 slots x 4 floats */
#define OFF_DONE  (OFF_FLG + 4096)         /* 16 x 16 floats */
#define OFF_VC    (OFF_DONE + 256)
#define OFF_MKEY  (OFF_VC + 16)            /* fp32 [32][128][512] */
#define OFF_WHT   (OFF_MKEY + 2097152)     /* unused */
#define OFF_WCTX  (OFF_WHT + 262144)       /* fp32 [2048][32] */
#define OFF_X     (OFF_WCTX + 65536)       /* fp32 [2048][320]; HBF reuses after p2c */
#define OFF_W0    (OFF_X + 655360)         /* fp32 [2048][320] */
#define OFF_HBF   OFF_X                    /* bf16 [2048][512] */
#define OFF_FCWBF (OFF_X + 524288)         /* bf16 [32000][512] -> 8192000 floats */

// step-unique buffers in the LOGITS region of d_out (each slot written before
// read every call; fc_gemm fully overwrites logits afterwards)
#define O_H1S  0              /* fp32 [64][4][512][8]  */
#define O_H2S  1048576        /* fp32 [65][4][512][8]  */
#define O_QS   2113536        /* fp32 [64][32][512]    */
#define O_CTXP 3162112        /* fp32 [64][32][8][32]  */
#define O_DENP 3686400        /* fp32 [64][32][8]      */
#define O_ES   3702784        /* fp32 [64][32][128]    */

// output offsets (float units)
#define OUT_HF  65536000
#define OUT_CF  65568768
#define OUT_ATT 65601536

// scan LDS map (floats)
#define L_HS2   0        /* [8][512] */
#define L_HS1   4096     /* [8][512] */
#define L_GL    8192     /* [32][9]  */
#define L_PG0   8480     /* [32][8]  */
#define L_C1    8736     /* [64]     */
#define L_C2    8800     /* [64]     */
#define L_CTX   8864     /* [8][33]  */
#define L_DEN   9128     /* [8]      */
#define L_QL    9136     /* [528]    */
#define L_VL    9664     /* [528]    */
#define L_SP    10192    /* [16][17] */
#define L_ESL   10464    /* [16]     */
#define L_CP    10480    /* [32][17] */
#define L_W0    11024    /* [32][512] whh0 WG rows, resident all 64 steps */
#define L_MK    27408    /* [16][16*33] mkey slice (padded), resident */
#define L_WH    35856    /* [8][512] wh WG rows, resident */
#define SCAN_LDS_FLOATS 39952
#define SCAN_LDS_BYTES  (SCAN_LDS_FLOATS*4)

typedef __attribute__((ext_vector_type(8))) short short8;
typedef __attribute__((ext_vector_type(4))) float f32x4;
typedef unsigned short u16;

__device__ __forceinline__ float frcp(float x){ return __builtin_amdgcn_rcpf(x); }
__device__ __forceinline__ float ftanh(float x){
  float e = __expf(2.0f*x);
  return 1.0f - 2.0f*frcp(e+1.0f);
}
__device__ __forceinline__ float fsig(float x){
  return frcp(1.0f + __expf(-x));
}
__device__ __forceinline__ u16 f2bf(float f){
  __hip_bfloat16 h = __float2bfloat16(f);
  u16 r; __builtin_memcpy(&r, &h, 2); return r;
}

// ---- coherent (write-through) access for flags + cross-WG producer stores ----
__device__ __forceinline__ float ldc1(const float* p){
  return __hip_atomic_load(p, __ATOMIC_RELAXED, __HIP_MEMORY_SCOPE_AGENT);
}
__device__ __forceinline__ void stc1(float* p, float v){
  __hip_atomic_store(p, v, __ATOMIC_RELAXED, __HIP_MEMORY_SCOPE_AGENT);
}

// ---- flag/aggregator barrier: busy-wait (R16-verified) ----
__device__ __forceinline__ void flag_store(float* ws, int c, int slot, float v){
  stc1(ws + OFF_FLG + c*256 + slot*4, v);
}
__device__ __forceinline__ void aggregate(float* ws, int c, float tgt, int tid){
  if (tid < 64){
    const float* fl = ws + OFF_FLG + c*256;
    unsigned cc = 0;
    while (true){
      float v = ldc1(fl + tid*4);
      if (__ballot(v >= tgt) == ~0ull) break;
      if (++cc >= (1u<<22)) break;   // terminate rather than hang
    }
    if (tid == 0) stc1(ws + OFF_DONE + c*16, tgt);
  }
}
__device__ __forceinline__ void waitD(float* ws, int c, float tgt){
  __syncthreads();
  if (threadIdx.x == 0){
    unsigned cc = 0;
    while (ldc1(ws + OFF_DONE + c*16) < tgt){
      if (++cc >= (1u<<24)) break;   // terminate rather than hang
    }
  }
  __syncthreads();
  asm volatile("" ::: "memory");
}

// 32-value reduce-scatter over 64 lanes; owner slot = bitrev5(L&31) for L<32.
__device__ __forceinline__ float redux32(float (&v)[32], int L){
  #pragma unroll
  for (int i=0;i<5;i++){
    const int m = 1<<i, h = 16>>i;
    const bool up = (L & m);
    #pragma unroll
    for (int u=0; u<h; u++){
      float send = up ? v[u] : v[u+h];
      float keep = up ? v[u+h] : v[u];
      v[u] = keep + __shfl_xor(send, m, 64);
    }
  }
  v[0] += __shfl_xor(v[0], 32, 64);
  return v[0];
}
// 16-value version: slot = bitrev4(L&15) for L<16
__device__ __forceinline__ float redux16(float (&v)[16], int L){
  #pragma unroll
  for (int i=0;i<4;i++){
    const int m = 1<<i, h = 8>>i;
    const bool up = (L & m);
    #pragma unroll
    for (int u=0; u<h; u++){
      float send = up ? v[u] : v[u+h];
      float keep = up ? v[u+h] : v[u];
      v[u] = keep + __shfl_xor(send, m, 64);
    }
  }
  v[0] += __shfl_xor(v[0], 16, 64);
  v[0] += __shfl_xor(v[0], 32, 64);
  return v[0];
}

// ---------------- P1: midi_proj (f32) + midi_key (f32) ----------------
__global__ __launch_bounds__(1024) void p1_midi(
    const float* __restrict__ midi, const float* __restrict__ mp_w,
    const float* __restrict__ mp_b, const float* __restrict__ wm,
    float* __restrict__ ws)
{
  __shared__ float ms[NFn*Dn];
  __shared__ float pj[NFn*33];
  __shared__ float mpw[Dn*33];
  __shared__ float mpb[Dn];
  int b = blockIdx.x, tid = threadIdx.x;
  for (int i=tid;i<NFn*Dn;i+=1024) ms[i] = midi[b*NFn*Dn + i];
  { int e = tid>>5, d = tid&31; mpw[e*33+d] = mp_w[tid]; }
  if (tid < Dn) mpb[tid] = mp_b[tid];
  __syncthreads();
  float* mproj = ws + OFF_MPROJ;
  for (int i=tid;i<NFn*Dn;i+=1024){
    int f = i>>5, e = i&31;
    float a = mpb[e];
    #pragma unroll
    for (int d=0;d<Dn;d++) a += ms[f*32+d]*mpw[e*33+d];
    a = fmaxf(a, 0.0f);
    pj[f*33+e] = a;
    mproj[b*NFn*Dn + i] = a;
  }
  __syncthreads();
  int h = tid & 511, fh = tid >> 9;
  float wreg[32];
  #pragma unroll
  for (int d=0;d<32;d++) wreg[d] = wm[h*32+d];
  float* mkf = ws + OFF_MKEY + b*(NFn*Hn);
  for (int ff=0; ff<64; ff++){
    int f = fh*64 + ff;
    float a = 0.f;
    #pragma unroll
    for (int d=0;d<32;d++) a += pj[f*33+d]*wreg[d];
    mkf[f*512 + h] = a;
  }
}

// ---------------- P2a: gather embeddings -> f32 X[2048][320] ----------------
__global__ __launch_bounds__(256) void p2a_x(
    const int* __restrict__ seq, const float* __restrict__ emb,
    float* __restrict__ ws)
{
  int idx = blockIdx.x*256 + threadIdx.x;
  int bt = idx / 80, c4 = idx - bt*80;
  int b = bt & 31, t = bt >> 5;
  float4 x = {0.f,0.f,0.f,0.f};
  if (c4 < 75){
    int s = seq[b*Tn + t];
    x = *(const float4*)(emb + (long)s*En + c4*4);
  }
  *(float4*)(ws + OFF_X + bt*320 + c4*4) = x;
}

// ---------------- P2b: wih0[:, :300] -> f32 [2048][320] padded ----------------
__global__ __launch_bounds__(256) void p2b_w(
    const float* __restrict__ wih0, float* __restrict__ ws)
{
  int idx = blockIdx.x*256 + threadIdx.x;
  int j = idx / 80, c4 = idx - j*80;
  float4 x = {0.f,0.f,0.f,0.f};
  if (c4 < 75) x = *(const float4*)(wih0 + (long)j*LIN + c4*4);
  *(float4*)(ws + OFF_W0 + j*320 + c4*4) = x;
}

// ---------------- P2c: E0 = W0 @ X^T + bias (fp32 SGEMM 128x128x32) ----------------
// E0 layout: [t][bg(4)][2048 rows][8 b]
__global__ __launch_bounds__(256) void p2c_e0(
    const float* __restrict__ ws_c, const float* __restrict__ bih0,
    const float* __restrict__ bhh0, float* __restrict__ ws)
{
  const float* A  = ws_c + OFF_W0;
  const float* Bm = ws_c + OFF_X;
  __shared__ float Al[32][132];
  __shared__ float Bl[32][132];
  int tid = threadIdx.x;
  int j0t = blockIdx.x*128, bt0 = blockIdx.y*128;
  int tx = tid & 15, ty = tid >> 4;
  float acc[8][8];
  #pragma unroll
  for (int i=0;i<8;i++)
    #pragma unroll
    for (int j=0;j<8;j++) acc[i][j] = 0.f;

  int m = tid >> 1;
  int kq = (tid & 1) * 16;
  for (int kk=0; kk<320; kk+=32){
    __syncthreads();
    {
      const float* As = A  + (long)(j0t+m)*320 + kk + kq;
      const float* Bs = Bm + (long)(bt0+m)*320 + kk + kq;
      float4 a0 = *(const float4*)(As+0), a1 = *(const float4*)(As+4);
      float4 a2 = *(const float4*)(As+8), a3 = *(const float4*)(As+12);
      float4 b0 = *(const float4*)(Bs+0), b1 = *(const float4*)(Bs+4);
      float4 b2 = *(const float4*)(Bs+8), b3 = *(const float4*)(Bs+12);
      Al[kq+0][m]=a0.x; Al[kq+1][m]=a0.y; Al[kq+2][m]=a0.z; Al[kq+3][m]=a0.w;
      Al[kq+4][m]=a1.x; Al[kq+5][m]=a1.y; Al[kq+6][m]=a1.z; Al[kq+7][m]=a1.w;
      Al[kq+8][m]=a2.x; Al[kq+9][m]=a2.y; Al[kq+10][m]=a2.z; Al[kq+11][m]=a2.w;
      Al[kq+12][m]=a3.x; Al[kq+13][m]=a3.y; Al[kq+14][m]=a3.z; Al[kq+15][m]=a3.w;
      Bl[kq+0][m]=b0.x; Bl[kq+1][m]=b0.y; Bl[kq+2][m]=b0.z; Bl[kq+3][m]=b0.w;
      Bl[kq+4][m]=b1.x; Bl[kq+5][m]=b1.y; Bl[kq+6][m]=b1.z; Bl[kq+7][m]=b1.w;
      Bl[kq+8][m]=b2.x; Bl[kq+9][m]=b2.y; Bl[kq+10][m]=b2.z; Bl[kq+11][m]=b2.w;
      Bl[kq+12][m]=b3.x; Bl[kq+13][m]=b3.y; Bl[kq+14][m]=b3.z; Bl[kq+15][m]=b3.w;
    }
    __syncthreads();
    #pragma unroll 4
    for (int k=0;k<32;k++){
      float4 a0 = *(const float4*)&Al[k][ty*8];
      float4 a1 = *(const float4*)&Al[k][ty*8+4];
      float4 b0 = *(const float4*)&Bl[k][tx*8];
      float4 b1 = *(const float4*)&Bl[k][tx*8+4];
      float av[8] = {a0.x,a0.y,a0.z,a0.w,a1.x,a1.y,a1.z,a1.w};
      float bv[8] = {b0.x,b0.y,b0.z,b0.w,b1.x,b1.y,b1.z,b1.w};
      #pragma unroll
      for (int i=0;i<8;i++)
        #pragma unroll
        for (int j=0;j<8;j++) acc[i][j] += av[i]*bv[j];
    }
  }
  float* E0 = ws + OFF_E0;
  #pragma unroll
  for (int i=0;i<8;i++){
    int j = j0t + ty*8 + i;
    float be = bih0[j] + bhh0[j];
    #pragma unroll
    for (int jj=0;jj<8;jj++){
      int c = bt0 + tx*8 + jj;
      int tt = c >> 5, bb = c & 31;
      E0[tt*65536 + (bb>>3)*16384 + j*8 + (bb&7)] = acc[i][jj] + be;
    }
  }
}

// ---------------- P3: fc_w -> bf16 ----------------
__global__ __launch_bounds__(256) void p3_cvt(
    const float* __restrict__ fcw, float* __restrict__ ws)
{
  u16* dst = (u16*)(ws + OFF_FCWBF);
  int base = (blockIdx.x*256 + threadIdx.x)*8;
  float4 x = *(const float4*)(fcw+base);
  float4 y = *(const float4*)(fcw+base+4);
  short8 p;
  p[0]=(short)f2bf(x.x); p[1]=(short)f2bf(x.y); p[2]=(short)f2bf(x.z); p[3]=(short)f2bf(x.w);
  p[4]=(short)f2bf(y.x); p[5]=(short)f2bf(y.y); p[6]=(short)f2bf(y.z); p[7]=(short)f2bf(y.w);
  *(short8*)(dst+base) = p;
}

// ---------------- P5: wih0[:,300:332] -> f32 [2048][32] ----------------
__global__ __launch_bounds__(256) void p5_wctx(
    const float* __restrict__ wih0, float* __restrict__ ws)
{
  int idx = blockIdx.x*256 + threadIdx.x;
  int j = idx >> 5, d = idx & 31;
  ws[OFF_WCTX + idx] = wih0[(long)j*LIN + En + d];
}

// ---------------- P6: C = sum |v| ----------------
__global__ __launch_bounds__(512) void p6_vc(
    const float* __restrict__ v, float* __restrict__ ws)
{
  __shared__ float s[8];
  int tid = threadIdx.x;
  float a = fabsf(v[tid]);
  #pragma unroll
  for (int m=1;m<64;m<<=1) a += __shfl_xor(a, m, 64);
  if ((tid&63)==0) s[tid>>6] = a;
  __syncthreads();
  if (tid==0){
    float c=0;
    #pragma unroll
    for (int i=0;i<8;i++) c += s[i];
    ws[OFF_VC] = c;
  }
}

// ---------------- P0: zero H2S slot 0 (in out) + flags (in ws) ----------------
__global__ __launch_bounds__(256) void p0_init(float* __restrict__ ws,
                                               float* __restrict__ out){
  int idx = blockIdx.x*256 + threadIdx.x;   // grid 64 -> 16384
  out[O_H2S + idx] = 0.f;
  if (idx < 4352) ws[OFF_FLG + idx] = 0.f;  // FLG[16][64][4] + DONE[16][16]
}

// ---------------- fused 64-step scan: 256 WGs x 256 thr (1 wave/SIMD) ----------------
__global__ __launch_bounds__(256, 1)
void scan_all(
    const float* __restrict__ wih1, const float* __restrict__ whh1,
    const float* __restrict__ whh0, const float* __restrict__ bih1,
    const float* __restrict__ bhh1, const float* __restrict__ wh,
    const float* __restrict__ vvec, float* __restrict__ ws,
    float* __restrict__ out)
{
  extern __shared__ float lds[];
  float* hs2  = lds + L_HS2;    // [8 b][512 k]  h2(t-1)
  float* hs1  = lds + L_HS1;    // [8 b][512 k]  h1(t)
  float* gl   = lds + L_GL;     // [32][9]
  float* pg0l = lds + L_PG0;    // [32][8]
  float* c1l  = lds + L_C1;     // [64]
  float* c2l  = lds + L_C2;     // [64]
  float* ctxl = lds + L_CTX;    // [8][33]
  float* denl = lds + L_DEN;    // [8]
  float* ql   = lds + L_QL;     // [528] padded
  float* vl   = lds + L_VL;     // [528]
  float* sp   = lds + L_SP;     // [16][17]
  float* esl  = lds + L_ESL;    // [16]
  float* cp   = lds + L_CP;     // [32][17]
  float* w0l  = lds + L_W0;     // [32][512] whh0 rows (persist 64 steps)
  float* mkl  = lds + L_MK;     // [16][16*33] mkey slice, bank-padded
  float* whl  = lds + L_WH;     // [8][512] wh rows

  const int wg = blockIdx.x, tid = threadIdx.x;
  const int rg = wg >> 2, bg = wg & 3;          // P1/P3/P4 identity
  const int b2 = wg >> 3, fs = wg & 7;          // P2 identity (batch b2, f-slice fs)
  const int bgp = wg >> 6;
  const int wv = tid >> 6, L = tid & 63;
  u16* hbf = (u16*)(ws + OFF_HBF);

  // ---- persistent per-lane weights: wih1/whh1, 128 VGPR, loaded once ----
  float w_a[8][8], w_b[8][8];
  #pragma unroll
  for (int r=0;r<8;r++){
    int row = wv*512 + rg*8 + r;
    #pragma unroll
    for (int j=0;j<8;j++){
      w_a[r][j] = wih1[(long)row*512 + j*64 + L];
      w_b[r][j] = whh1[(long)row*512 + j*64 + L];
    }
  }
  // ---- whh0 WG rows -> LDS, loaded once ----
  for (int c=0; c<64; c++){
    int idx = c*256 + tid;          // 0..16383
    int lr = idx >> 9, k = idx & 511;
    int grow = (lr>>3)*512 + rg*8 + (lr&7);
    w0l[idx] = whh0[(long)grow*512 + k];
  }
  // ---- mkey slice (b2, rows fs*16..fs*16+15) -> LDS, padded, loaded once ----
  for (int c=0; c<32; c++){
    int idx = c*256 + tid;          // 0..8191
    int f = idx >> 9, r = idx & 511;
    mkl[f*528 + (r>>5)*33 + (r&31)] =
        ws[OFF_MKEY + b2*65536 + (fs*16+f)*512 + r];
  }
  // ---- wh rows rg*8..rg*8+7 -> LDS, loaded once ----
  for (int c=0; c<16; c++){
    int idx = c*256 + tid;          // 0..4095
    whl[idx] = wh[(long)(rg*8)*512 + idx];
  }

  // lane redux constants
  const int s4 = ((L&1)<<3) | ((L&2)<<1) | ((L&4)>>1) | ((L&8)>>3);
  const int q_sr = s4 >> 3, q_sx = s4 & 7;                       // redux16 owner (L<16)
  const int s5 = ((L&1)<<4) | ((L&2)<<2) | (L&4) | ((L&8)>>2) | ((L&16)>>4);
  const int r_sr = s5 >> 3, r_sx = s5 & 7;                       // redux32 owner (L<32)
  float bsum[2]; int glIdx[2], pgIdx[2];
  #pragma unroll
  for (int p=0;p<2;p++){
    int kk = p*4 + r_sr;
    int row = wv*512 + rg*8 + kk;
    bsum[p] = bih1[row] + bhh1[row];
    glIdx[p] = (wv*8 + kk)*9 + r_sx;
    pgIdx[p] = (wv*8 + kk)*8 + r_sx;
  }

  // ---- persistent LDS init ----
  if (tid < 64){ c1l[tid] = 0.f; c2l[tid] = 0.f; }
  {
    int r = tid>>3, bb = tid&7;
    int row = ((r>>3)<<9) + rg*8 + (r&7);
    pg0l[r*8+bb] = ws[OFF_E0 + bg*16384 + row*8 + bb];   // pg0(0) = E0[0]
  }
  vl[tid + (tid>>5)] = vvec[tid];
  { int t2 = tid + 256; vl[t2 + (t2>>5)] = vvec[t2]; }
  const float Cv = ws[OFF_VC];
  __syncthreads();

  for (int t=0; t<64; t++){
    const float tgt = (float)(t+1);
    // ================= P1: q = wh @ h2(t-1) =================
    if (t > 0) waitD(ws, 0+bg, (float)t);
    {
      const float* h2b = out + O_H2S + t*16384 + bg*4096;
      float4 v0 = *(const float4*)(h2b +    0 + tid*4);
      float4 v1 = *(const float4*)(h2b + 1024 + tid*4);
      float4 v2 = *(const float4*)(h2b + 2048 + tid*4);
      float4 v3 = *(const float4*)(h2b + 3072 + tid*4);
      int kb = tid >> 1, bb0 = (tid&1)*4;
      hs2[(bb0+0)*512 +   0 + kb] = v0.x; hs2[(bb0+1)*512 +   0 + kb] = v0.y;
      hs2[(bb0+2)*512 +   0 + kb] = v0.z; hs2[(bb0+3)*512 +   0 + kb] = v0.w;
      hs2[(bb0+0)*512 + 128 + kb] = v1.x; hs2[(bb0+1)*512 + 128 + kb] = v1.y;
      hs2[(bb0+2)*512 + 128 + kb] = v1.z; hs2[(bb0+3)*512 + 128 + kb] = v1.w;
      hs2[(bb0+0)*512 + 256 + kb] = v2.x; hs2[(bb0+1)*512 + 256 + kb] = v2.y;
      hs2[(bb0+2)*512 + 256 + kb] = v2.z; hs2[(bb0+3)*512 + 256 + kb] = v2.w;
      hs2[(bb0+0)*512 + 384 + kb] = v3.x; hs2[(bb0+1)*512 + 384 + kb] = v3.y;
      hs2[(bb0+2)*512 + 384 + kb] = v3.z; hs2[(bb0+3)*512 + 384 + kb] = v3.w;
    }
    __syncthreads();
    {
      const float* w0p = whl + (wv*2)*512;     // LDS-resident wh rows
      const float* w1p = w0p + 512;
      float vq[16];
      #pragma unroll
      for (int i=0;i<16;i++) vq[i] = 0.f;
      #pragma unroll
      for (int j=0;j<8;j++){
        int k = j*64 + L;
        float wa = w0p[k], wb = w1p[k];
        #pragma unroll
        for (int x=0;x<8;x++){
          float hv = hs2[x*512+k];
          vq[x] += wa*hv; vq[8+x] += wb*hv;
        }
      }
      float qv = redux16(vq, L);
      if (L < 16)
        stc1(out + O_QS + t*16384 + (bg*8+q_sx)*512 + rg*8 + wv*2 + q_sr, qv);
    }
    __syncthreads();
    if (tid == 0) flag_store(ws, 4+bg, wg>>2, tgt);
    if (wg < 4) aggregate(ws, 4+wg, tgt, tid);

    // ================= P2: scores / exp / ctx-partials =================
    waitD(ws, 4+bgp, tgt);
    ql[tid + (tid>>5)] = out[O_QS + t*16384 + b2*512 + tid];
    { int t2 = tid + 256; ql[t2 + (t2>>5)] = out[O_QS + t*16384 + b2*512 + t2]; }
    __syncthreads();
    {
      int f = tid>>4, hg = tid&15;
      const float* mkr = mkl + f*528 + hg*33;   // LDS-resident mkey slice
      const float* qb = ql + hg*33;
      const float* vb = vl + hg*33;
      float s = 0.f;
      #pragma unroll
      for (int c=0; c<32; c+=4){
        float4 m4 = *(const float4*)(mkr+c);
        s += vb[c+0]*ftanh(qb[c+0]+m4.x) + vb[c+1]*ftanh(qb[c+1]+m4.y)
           + vb[c+2]*ftanh(qb[c+2]+m4.z) + vb[c+3]*ftanh(qb[c+3]+m4.w);
      }
      sp[f*17+hg] = s;
    }
    __syncthreads();
    if (tid < 16){
      float s = 0.f;
      #pragma unroll
      for (int g=0; g<16; g++) s += sp[tid*17+g];
      float e = __expf(s - Cv);
      esl[tid] = e;
      stc1(out + O_ES + t*4096 + b2*128 + fs*16 + tid, e);
    }
    __syncthreads();
    if (tid == 0){
      float d = 0.f;
      #pragma unroll
      for (int i=0;i<16;i++) d += esl[i];
      stc1(out + O_DENP + t*256 + b2*8 + fs, d);
    }
    {
      int d2 = tid&31, f0 = tid>>5;
      cp[d2*17+f0]   = esl[f0]  * ws[OFF_MPROJ + b2*4096 + (fs*16+f0)*32   + d2];
      cp[d2*17+f0+8] = esl[f0+8]* ws[OFF_MPROJ + b2*4096 + (fs*16+f0+8)*32 + d2];
    }
    __syncthreads();
    if (tid < 32){
      float s = 0.f;
      #pragma unroll
      for (int ff=0; ff<16; ff++) s += cp[tid*17+ff];
      stc1(out + O_CTXP + t*8192 + b2*256 + fs*32 + tid, s);
    }
    __syncthreads();
    if (tid == 0) flag_store(ws, 8+bgp, wg&63, tgt);
    if ((wg&63) == 0) aggregate(ws, 8+bgp, tgt, tid);

    // ================= P3: ctx gather + gates0 + cell1 =================
    waitD(ws, 8+bg, tgt);
    if (tid < 8){
      float dsum = 0.f;
      #pragma unroll
      for (int f2=0; f2<8; f2++) dsum += out[O_DENP + t*256 + (bg*8+tid)*8 + f2];
      denl[tid] = frcp(dsum);
    }
    __syncthreads();
    {
      int bb = tid>>5, d = tid&31;
      float s = 0.f;
      #pragma unroll
      for (int f2=0; f2<8; f2++) s += out[O_CTXP + t*8192 + (bg*8+bb)*256 + f2*32 + d];
      ctxl[bb*33+d] = s * denl[bb];
    }
    if (rg == 0){
      #pragma unroll
      for (int i0=0; i0<4; i0++){
        int i = tid + i0*256;
        int bb = i>>7, f = i&127;
        float e = out[O_ES + t*4096 + (bg*8+bb)*128 + f];
        __builtin_nontemporal_store(e * denl[bb],
            out + OUT_ATT + (bg*8+bb)*8192 + t*128 + f);
      }
    }
    __syncthreads();
    {
      int r = tid>>3, bb = tid&7;
      int row = ((r>>3)<<9) + rg*8 + (r&7);
      float g0 = pg0l[r*8+bb];
      const float* wr = ws + OFF_WCTX + row*32;
      #pragma unroll
      for (int d2=0; d2<32; d2+=4){
        float4 w4 = *(const float4*)(wr+d2);
        g0 += w4.x*ctxl[bb*33+d2] + w4.y*ctxl[bb*33+d2+1]
            + w4.z*ctxl[bb*33+d2+2] + w4.w*ctxl[bb*33+d2+3];
      }
      gl[r*9+bb] = g0;
    }
    __syncthreads();
    if (tid < 64){
      int kk = tid>>3, bb = tid&7;
      float gi = gl[(kk)*9+bb],     gf = gl[(8+kk)*9+bb];
      float gg2 = gl[(16+kk)*9+bb], go = gl[(24+kk)*9+bb];
      float cp2 = c1l[tid];
      float cn = fsig(gf)*cp2 + fsig(gi)*ftanh(gg2);
      float hn = fsig(go)*ftanh(cn);
      c1l[tid] = cn;
      stc1(out + O_H1S + t*16384 + bg*4096 + (rg*8+kk)*8 + bb, hn);
      if (t == 63){
        int bgl = bg*8+bb, kgl = rg*8+kk;
        __builtin_nontemporal_store(hn, out + OUT_HF + bgl*512 + kgl);
        __builtin_nontemporal_store(cn, out + OUT_CF + bgl*512 + kgl);
      }
    }
    __syncthreads();
    if (tid == 0) flag_store(ws, 12+bg, wg>>2, tgt);
    if (wg < 4) aggregate(ws, 12+wg, tgt, tid);

    // ================= P4: gates1 + cell2 (+ pg0(t+1) off critical path) ======
    waitD(ws, 12+bg, tgt);
    {
      const float* h1b = out + O_H1S + t*16384 + bg*4096;
      float4 v0 = *(const float4*)(h1b +    0 + tid*4);
      float4 v1 = *(const float4*)(h1b + 1024 + tid*4);
      float4 v2 = *(const float4*)(h1b + 2048 + tid*4);
      float4 v3 = *(const float4*)(h1b + 3072 + tid*4);
      int kb = tid >> 1, bb0 = (tid&1)*4;
      hs1[(bb0+0)*512 +   0 + kb] = v0.x; hs1[(bb0+1)*512 +   0 + kb] = v0.y;
      hs1[(bb0+2)*512 +   0 + kb] = v0.z; hs1[(bb0+3)*512 +   0 + kb] = v0.w;
      hs1[(bb0+0)*512 + 128 + kb] = v1.x; hs1[(bb0+1)*512 + 128 + kb] = v1.y;
      hs1[(bb0+2)*512 + 128 + kb] = v1.z; hs1[(bb0+3)*512 + 128 + kb] = v1.w;
      hs1[(bb0+0)*512 + 256 + kb] = v2.x; hs1[(bb0+1)*512 + 256 + kb] = v2.y;
      hs1[(bb0+2)*512 + 256 + kb] = v2.z; hs1[(bb0+3)*512 + 256 + kb] = v2.w;
      hs1[(bb0+0)*512 + 384 + kb] = v3.x; hs1[(bb0+1)*512 + 384 + kb] = v3.y;
      hs1[(bb0+2)*512 + 384 + kb] = v3.z; hs1[(bb0+3)*512 + 384 + kb] = v3.w;
    }
    __syncthreads();
    // gates1 = wih1 @ h1 + whh1 @ h2(t-1): two passes of 4 rows x 8 b
    #pragma unroll
    for (int p=0; p<2; p++){
      float vals[32];
      #pragma unroll
      for (int i=0;i<32;i++) vals[i] = 0.f;
      #pragma unroll
      for (int j=0;j<8;j++){
        int k = j*64 + L;
        float h1v[8], h2v[8];
        #pragma unroll
        for (int x=0;x<8;x++){ h1v[x] = hs1[x*512+k]; h2v[x] = hs2[x*512+k]; }
        #pragma unroll
        for (int r=0;r<4;r++){
          const float wa = w_a[p*4+r][j], wb = w_b[p*4+r][j];
          #pragma unroll
          for (int x=0;x<8;x++) vals[r*8+x] += wa*h1v[x] + wb*h2v[x];
        }
      }
      float v0 = redux32(vals, L);
      if (L < 32) gl[glIdx[p]] = v0 + bsum[p];
    }
    __syncthreads();
    if (tid < 64){
      int kk = tid>>3, bb = tid&7;
      float gi = gl[(kk)*9+bb],     gf = gl[(8+kk)*9+bb];
      float gg2 = gl[(16+kk)*9+bb], go = gl[(24+kk)*9+bb];
      float cp3 = c2l[tid];
      float cn = fsig(gf)*cp3 + fsig(gi)*ftanh(gg2);
      float hn = fsig(go)*ftanh(cn);
      c2l[tid] = cn;
      int k2 = rg*8+kk, b = bg*8+bb;
      stc1(out + O_H2S + (t+1)*16384 + bg*4096 + k2*8 + bb, hn);
      __builtin_nontemporal_store(f2bf(hn), hbf + (t*32+b)*512 + k2);
      if (t == 63){
        __builtin_nontemporal_store(hn, out + OUT_HF + 16384 + b*512 + k2);
        __builtin_nontemporal_store(cn, out + OUT_CF + 16384 + b*512 + k2);
      }
    }
    __syncthreads();                 // drains h2 stores before signal
    if (tid == 0) flag_store(ws, 0+bg, wg>>2, tgt);
    if (wg < 4) aggregate(ws, 0+wg, tgt, tid);

    // pg0(t+1) = whh0 @ h1 (+ E0[t+1]) — whh0 in LDS, WG-local consumer
    if (t < 63){
      #pragma unroll
      for (int p=0; p<2; p++){
        float vals[32];
        #pragma unroll
        for (int i=0;i<32;i++) vals[i] = 0.f;
        #pragma unroll
        for (int j=0;j<8;j++){
          int k = j*64 + L;
          float h1v[8];
          #pragma unroll
          for (int x=0;x<8;x++) h1v[x] = hs1[x*512+k];
          #pragma unroll
          for (int r=0;r<4;r++){
            const float wc = w0l[(wv*8 + p*4 + r)*512 + k];
            #pragma unroll
            for (int x=0;x<8;x++) vals[r*8+x] += wc*h1v[x];
          }
        }
        float v0 = redux32(vals, L);
        if (L < 32) pg0l[pgIdx[p]] = v0;
      }
      __syncthreads();
      {
        int r = tid>>3, bb = tid&7;
        int row = ((r>>3)<<9) + rg*8 + (r&7);
        pg0l[r*8+bb] += __builtin_nontemporal_load(
            ws + OFF_E0 + (t+1)*65536 + bg*16384 + row*8 + bb);
      }
    }
    // loop-top waitD's __syncthreads orders pg0l for next P3
  }
}

// ---------------- FC: logits = h @ fc_w^T + fc_b (bf16 MFMA) ----------------
__global__ __launch_bounds__(256) void fc_gemm(
    const float* __restrict__ ws_f, const float* __restrict__ fcb,
    float* __restrict__ out)
{
  const u16* A  = (const u16*)(ws_f + OFF_FCWBF);
  const u16* Bm = (const u16*)(ws_f + OFF_HBF);
  __shared__ u16 Al[128*40];
  __shared__ u16 Bl[128*40];
  int tid = threadIdx.x;
  int v0 = blockIdx.x*128, bt0 = blockIdx.y*128;
  int lane = tid & 63, wv = tid >> 6;
  int wr = wv >> 1, wc = wv & 1;
  f32x4 acc[4][4];
  #pragma unroll
  for (int i=0;i<4;i++)
    #pragma unroll
    for (int j=0;j<4;j++) acc[i][j] = (f32x4){0.f,0.f,0.f,0.f};

  int ar = wr*64 + (lane&15);
  int br = wc*64 + (lane&15);
  int ks = (lane>>4)*8;

  for (int kk=0; kk<512; kk+=32){
    __syncthreads();
    #pragma unroll
    for (int i=0;i<2;i++){
      int ld = tid + 256*i;
      int row = ld >> 2, cs = (ld & 3)*8;
      *(int4*)(&Al[row*40+cs]) = *(const int4*)(A  + (v0+row)*512 + kk + cs);
      *(int4*)(&Bl[row*40+cs]) = *(const int4*)(Bm + (bt0+row)*512 + kk + cs);
    }
    __syncthreads();
    short8 af[4], bf[4];
    #pragma unroll
    for (int m=0;m<4;m++) af[m] = *(const short8*)(&Al[(ar+m*16)*40 + ks]);
    #pragma unroll
    for (int n=0;n<4;n++) bf[n] = *(const short8*)(&Bl[(br+n*16)*40 + ks]);
    #pragma unroll
    for (int m=0;m<4;m++)
      #pragma unroll
      for (int n=0;n<4;n++)
        acc[m][n] = __builtin_amdgcn_mfma_f32_16x16x32_bf16(af[m], bf[n], acc[m][n], 0,0,0);
  }
  int r4 = (lane>>4)*4;
  #pragma unroll
  for (int m=0;m<4;m++){
    int v = v0 + wr*64 + m*16 + r4;
    float4 bias = *(const float4*)(fcb + v);
    #pragma unroll
    for (int n=0;n<4;n++){
      int bt = bt0 + wc*64 + n*16 + (lane&15);
      int b = bt & 31, t = bt >> 5;
      f32x4 a = acc[m][n];
      float4 res = { a[0]+bias.x, a[1]+bias.y, a[2]+bias.z, a[3]+bias.w };
      *(float4*)(out + b*2048000 + t*32000 + v) = res;
    }
  }
}

extern "C" void kernel_launch(void* const* d_in, const int* in_sizes, int n_in,
                              void* d_out, int out_size, void* d_ws, size_t ws_size,
                              hipStream_t stream)
{
  const int*   seq  = (const int*)d_in[0];
  const float* midi = (const float*)d_in[1];
  const float* emb  = (const float*)d_in[2];
  const float* mpw  = (const float*)d_in[3];
  const float* mpb  = (const float*)d_in[4];
  const float* wh   = (const float*)d_in[5];
  const float* wm   = (const float*)d_in[6];
  const float* vv   = (const float*)d_in[7];
  const float* wih0 = (const float*)d_in[8];
  const float* whh0 = (const float*)d_in[9];
  const float* bih0 = (const float*)d_in[10];
  const float* bhh0 = (const float*)d_in[11];
  const float* wih1 = (const float*)d_in[12];
  const float* whh1 = (const float*)d_in[13];
  const float* bih1 = (const float*)d_in[14];
  const float* bhh1 = (const float*)d_in[15];
  const float* fcw  = (const float*)d_in[16];
  const float* fcb  = (const float*)d_in[17];
  float* out = (float*)d_out;
  float* ws  = (float*)d_ws;

  // allow >64KB dynamic LDS for the scan (host-side, capture-safe)
  hipFuncSetAttribute((const void*)scan_all,
                      hipFuncAttributeMaxDynamicSharedMemorySize,
                      SCAN_LDS_BYTES);

  p1_midi<<<32, 1024, 0, stream>>>(midi, mpw, mpb, wm, ws);
  p2a_x  <<<640, 256, 0, stream>>>(seq, emb, ws);
  p2b_w  <<<640, 256, 0, stream>>>(wih0, ws);
  p2c_e0 <<<dim3(16,16), 256, 0, stream>>>(ws, bih0, bhh0, ws);
  p3_cvt <<<8000, 256, 0, stream>>>(fcw, ws);
  p5_wctx<<<256, 256, 0, stream>>>(wih0, ws);
  p6_vc  <<<1, 512, 0, stream>>>(vv, ws);
  p0_init<<<64, 256, 0, stream>>>(ws, out);

  scan_all<<<NWG, 256, SCAN_LDS_BYTES, stream>>>(wih1, whh1, whh0, bih1, bhh1,
                                                 wh, vv, ws, out);

  fc_gemm<<<dim3(250,16), 256, 0, stream>>>(ws, fcb, out);
}

// Round 18
// 5542.249 us; speedup vs baseline: 1.0265x; 1.0043x over previous
//
#include <hip/hip_runtime.h>
#include <hip/hip_bf16.h>

#define Bsz 32
#define Tn  64
#define Vn  32000
#define En  300
#define Hn  512
#define NFn 128
#define Dn  32
#define G4  2048
#define LIN 332
#define NWG 256

// workspace offsets (float units)
#define OFF_MPROJ 0
#define OFF_E0    (OFF_MPROJ + 131072)     /* fp32 [64][4 bg][2048][8] */
#define OFF_PG0B  (OFF_E0 + 4194304)       /* legacy scratch (unused now) */
#define OFF_H1T   (OFF_PG0B + 65536)
#define OFF_H2T0  (OFF_H1T + 16384)
#define OFF_H2T1  (OFF_H2T0 + 16384)
#define OFF_H2BB  (OFF_H2T1 + 16384)
#define OFF_C1T   (OFF_H2BB + 16384)
#define OFF_C2T   (OFF_C1T + 16384)
#define OFF_FLG   (OFF_C2T + 16384)        /* 16 ctr x 64 slots x 4 floats */
#define OFF_DONE  (OFF_FLG + 4096)         /* unused */
#define OFF_VC    (OFF_DONE + 256)
#define OFF_MKEY  (OFF_VC + 16)            /* fp32 [32][128][512] */
#define OFF_WHT   (OFF_MKEY + 2097152)     /* unused */
#define OFF_WCTX  (OFF_WHT + 262144)       /* fp32 [2048][32] */
#define OFF_X     (OFF_WCTX + 65536)       /* fp32 [2048][320]; HBF reuses after p2c */
#define OFF_W0    (OFF_X + 655360)         /* fp32 [2048][320] */
#define OFF_HBF   OFF_X                    /* bf16 [2048][512] */
#define OFF_FCWBF (OFF_X + 524288)         /* bf16 [32000][512] -> 8192000 floats */

// step-unique buffers in the LOGITS region of d_out
#define O_H1S  0              /* fp32 [64][4][512][8]  */
#define O_H2S  1048576        /* fp32 [65][4][512][8]  */
#define O_QS   2113536        /* fp32 [64][32][512]    */
#define O_CTXP 3162112        /* fp32 [64][32][8][32]  */
#define O_DENP 3686400        /* fp32 [64][32][8]      */
#define O_ES   3702784        /* fp32 [64][32][128]    */

// output offsets (float units)
#define OUT_HF  65536000
#define OUT_CF  65568768
#define OUT_ATT 65601536

// scan LDS map (floats)
#define L_HS2   0        /* [8][512] */
#define L_HS1   4096     /* [8][512] */
#define L_GL    8192     /* [32][9]  */
#define L_PG0   8480     /* [32][8]  */
#define L_C1    8736     /* [64]     */
#define L_C2    8800     /* [64]     */
#define L_CTX   8864     /* [8][33]  */
#define L_DEN   9128     /* [8]      */
#define L_QL    9136     /* [528]    */
#define L_VL    9664     /* [528]    */
#define L_SP    10192    /* [16][17] */
#define L_ESL   10464    /* [16]     */
#define L_CP    10480    /* [32][17] */
#define L_W0    11024    /* [32][512] whh0 WG rows, resident all 64 steps */
#define L_MK    27408    /* [16][16*33] mkey slice (padded), resident */
#define L_WH    35856    /* [8][512] wh WG rows, resident */
#define SCAN_LDS_FLOATS 39952
#define SCAN_LDS_BYTES  (SCAN_LDS_FLOATS*4)

typedef __attribute__((ext_vector_type(8))) short short8;
typedef __attribute__((ext_vector_type(4))) float f32x4;
typedef unsigned short u16;

__device__ __forceinline__ float frcp(float x){ return __builtin_amdgcn_rcpf(x); }
__device__ __forceinline__ float ftanh(float x){
  float e = __expf(2.0f*x);
  return 1.0f - 2.0f*frcp(e+1.0f);
}
__device__ __forceinline__ float fsig(float x){
  return frcp(1.0f + __expf(-x));
}
__device__ __forceinline__ u16 f2bf(float f){
  __hip_bfloat16 h = __float2bfloat16(f);
  u16 r; __builtin_memcpy(&r, &h, 2); return r;
}

// ---- coherent (write-through) access for flags + cross-WG producer stores ----
__device__ __forceinline__ float ldc1(const float* p){
  return __hip_atomic_load(p, __ATOMIC_RELAXED, __HIP_MEMORY_SCOPE_AGENT);
}
__device__ __forceinline__ void stc1(float* p, float v){
  __hip_atomic_store(p, v, __ATOMIC_RELAXED, __HIP_MEMORY_SCOPE_AGENT);
}

// ---- direct group barrier: producer stores slot, every consumer ballot-polls
// its own group's 64 slots. ONE visibility round trip per hop, no aggregator.
__device__ __forceinline__ void flag_store(float* ws, int c, int slot, float v){
  stc1(ws + OFF_FLG + c*256 + slot*4, v);
}
__device__ __forceinline__ void waitA(float* ws, int c, float tgt, int tid){
  __syncthreads();
  if (tid < 64){
    const float* fl = ws + OFF_FLG + c*256;
    unsigned cc = 0;
    while (true){
      float v = ldc1(fl + tid*4);
      if (__ballot(v >= tgt) == ~0ull) break;
      if (++cc >= (1u<<22)) break;   // terminate rather than hang
    }
  }
  __syncthreads();
  asm volatile("" ::: "memory");
}

// 32-value reduce-scatter over 64 lanes; owner slot = bitrev5(L&31) for L<32.
__device__ __forceinline__ float redux32(float (&v)[32], int L){
  #pragma unroll
  for (int i=0;i<5;i++){
    const int m = 1<<i, h = 16>>i;
    const bool up = (L & m);
    #pragma unroll
    for (int u=0; u<h; u++){
      float send = up ? v[u] : v[u+h];
      float keep = up ? v[u+h] : v[u];
      v[u] = keep + __shfl_xor(send, m, 64);
    }
  }
  v[0] += __shfl_xor(v[0], 32, 64);
  return v[0];
}
// 16-value version: slot = bitrev4(L&15) for L<16
__device__ __forceinline__ float redux16(float (&v)[16], int L){
  #pragma unroll
  for (int i=0;i<4;i++){
    const int m = 1<<i, h = 8>>i;
    const bool up = (L & m);
    #pragma unroll
    for (int u=0; u<h; u++){
      float send = up ? v[u] : v[u+h];
      float keep = up ? v[u+h] : v[u];
      v[u] = keep + __shfl_xor(send, m, 64);
    }
  }
  v[0] += __shfl_xor(v[0], 16, 64);
  v[0] += __shfl_xor(v[0], 32, 64);
  return v[0];
}

// ---------------- P1: midi_proj (f32) + midi_key (f32) ----------------
__global__ __launch_bounds__(1024) void p1_midi(
    const float* __restrict__ midi, const float* __restrict__ mp_w,
    const float* __restrict__ mp_b, const float* __restrict__ wm,
    float* __restrict__ ws)
{
  __shared__ float ms[NFn*Dn];
  __shared__ float pj[NFn*33];
  __shared__ float mpw[Dn*33];
  __shared__ float mpb[Dn];
  int b = blockIdx.x, tid = threadIdx.x;
  for (int i=tid;i<NFn*Dn;i+=1024) ms[i] = midi[b*NFn*Dn + i];
  { int e = tid>>5, d = tid&31; mpw[e*33+d] = mp_w[tid]; }
  if (tid < Dn) mpb[tid] = mp_b[tid];
  __syncthreads();
  float* mproj = ws + OFF_MPROJ;
  for (int i=tid;i<NFn*Dn;i+=1024){
    int f = i>>5, e = i&31;
    float a = mpb[e];
    #pragma unroll
    for (int d=0;d<Dn;d++) a += ms[f*32+d]*mpw[e*33+d];
    a = fmaxf(a, 0.0f);
    pj[f*33+e] = a;
    mproj[b*NFn*Dn + i] = a;
  }
  __syncthreads();
  int h = tid & 511, fh = tid >> 9;
  float wreg[32];
  #pragma unroll
  for (int d=0;d<32;d++) wreg[d] = wm[h*32+d];
  float* mkf = ws + OFF_MKEY + b*(NFn*Hn);
  for (int ff=0; ff<64; ff++){
    int f = fh*64 + ff;
    float a = 0.f;
    #pragma unroll
    for (int d=0;d<32;d++) a += pj[f*33+d]*wreg[d];
    mkf[f*512 + h] = a;
  }
}

// ---------------- P2a: gather embeddings -> f32 X[2048][320] ----------------
__global__ __launch_bounds__(256) void p2a_x(
    const int* __restrict__ seq, const float* __restrict__ emb,
    float* __restrict__ ws)
{
  int idx = blockIdx.x*256 + threadIdx.x;
  int bt = idx / 80, c4 = idx - bt*80;
  int b = bt & 31, t = bt >> 5;
  float4 x = {0.f,0.f,0.f,0.f};
  if (c4 < 75){
    int s = seq[b*Tn + t];
    x = *(const float4*)(emb + (long)s*En + c4*4);
  }
  *(float4*)(ws + OFF_X + bt*320 + c4*4) = x;
}

// ---------------- P2b: wih0[:, :300] -> f32 [2048][320] padded ----------------
__global__ __launch_bounds__(256) void p2b_w(
    const float* __restrict__ wih0, float* __restrict__ ws)
{
  int idx = blockIdx.x*256 + threadIdx.x;
  int j = idx / 80, c4 = idx - j*80;
  float4 x = {0.f,0.f,0.f,0.f};
  if (c4 < 75) x = *(const float4*)(wih0 + (long)j*LIN + c4*4);
  *(float4*)(ws + OFF_W0 + j*320 + c4*4) = x;
}

// ---------------- P2c: E0 = W0 @ X^T + bias (fp32 SGEMM 128x128x32) ----------------
// E0 layout: [t][bg(4)][2048 rows][8 b]
__global__ __launch_bounds__(256) void p2c_e0(
    const float* __restrict__ ws_c, const float* __restrict__ bih0,
    const float* __restrict__ bhh0, float* __restrict__ ws)
{
  const float* A  = ws_c + OFF_W0;
  const float* Bm = ws_c + OFF_X;
  __shared__ float Al[32][132];
  __shared__ float Bl[32][132];
  int tid = threadIdx.x;
  int j0t = blockIdx.x*128, bt0 = blockIdx.y*128;
  int tx = tid & 15, ty = tid >> 4;
  float acc[8][8];
  #pragma unroll
  for (int i=0;i<8;i++)
    #pragma unroll
    for (int j=0;j<8;j++) acc[i][j] = 0.f;

  int m = tid >> 1;
  int kq = (tid & 1) * 16;
  for (int kk=0; kk<320; kk+=32){
    __syncthreads();
    {
      const float* As = A  + (long)(j0t+m)*320 + kk + kq;
      const float* Bs = Bm + (long)(bt0+m)*320 + kk + kq;
      float4 a0 = *(const float4*)(As+0), a1 = *(const float4*)(As+4);
      float4 a2 = *(const float4*)(As+8), a3 = *(const float4*)(As+12);
      float4 b0 = *(const float4*)(Bs+0), b1 = *(const float4*)(Bs+4);
      float4 b2 = *(const float4*)(Bs+8), b3 = *(const float4*)(Bs+12);
      Al[kq+0][m]=a0.x; Al[kq+1][m]=a0.y; Al[kq+2][m]=a0.z; Al[kq+3][m]=a0.w;
      Al[kq+4][m]=a1.x; Al[kq+5][m]=a1.y; Al[kq+6][m]=a1.z; Al[kq+7][m]=a1.w;
      Al[kq+8][m]=a2.x; Al[kq+9][m]=a2.y; Al[kq+10][m]=a2.z; Al[kq+11][m]=a2.w;
      Al[kq+12][m]=a3.x; Al[kq+13][m]=a3.y; Al[kq+14][m]=a3.z; Al[kq+15][m]=a3.w;
      Bl[kq+0][m]=b0.x; Bl[kq+1][m]=b0.y; Bl[kq+2][m]=b0.z; Bl[kq+3][m]=b0.w;
      Bl[kq+4][m]=b1.x; Bl[kq+5][m]=b1.y; Bl[kq+6][m]=b1.z; Bl[kq+7][m]=b1.w;
      Bl[kq+8][m]=b2.x; Bl[kq+9][m]=b2.y; Bl[kq+10][m]=b2.z; Bl[kq+11][m]=b2.w;
      Bl[kq+12][m]=b3.x; Bl[kq+13][m]=b3.y; Bl[kq+14][m]=b3.z; Bl[kq+15][m]=b3.w;
    }
    __syncthreads();
    #pragma unroll 4
    for (int k=0;k<32;k++){
      float4 a0 = *(const float4*)&Al[k][ty*8];
      float4 a1 = *(const float4*)&Al[k][ty*8+4];
      float4 b0 = *(const float4*)&Bl[k][tx*8];
      float4 b1 = *(const float4*)&Bl[k][tx*8+4];
      float av[8] = {a0.x,a0.y,a0.z,a0.w,a1.x,a1.y,a1.z,a1.w};
      float bv[8] = {b0.x,b0.y,b0.z,b0.w,b1.x,b1.y,b1.z,b1.w};
      #pragma unroll
      for (int i=0;i<8;i++)
        #pragma unroll
        for (int j=0;j<8;j++) acc[i][j] += av[i]*bv[j];
    }
  }
  float* E0 = ws + OFF_E0;
  #pragma unroll
  for (int i=0;i<8;i++){
    int j = j0t + ty*8 + i;
    float be = bih0[j] + bhh0[j];
    #pragma unroll
    for (int jj=0;jj<8;jj++){
      int c = bt0 + tx*8 + jj;
      int tt = c >> 5, bb = c & 31;
      E0[tt*65536 + (bb>>3)*16384 + j*8 + (bb&7)] = acc[i][jj] + be;
    }
  }
}

// ---------------- P3: fc_w -> bf16 ----------------
__global__ __launch_bounds__(256) void p3_cvt(
    const float* __restrict__ fcw, float* __restrict__ ws)
{
  u16* dst = (u16*)(ws + OFF_FCWBF);
  int base = (blockIdx.x*256 + threadIdx.x)*8;
  float4 x = *(const float4*)(fcw+base);
  float4 y = *(const float4*)(fcw+base+4);
  short8 p;
  p[0]=(short)f2bf(x.x); p[1]=(short)f2bf(x.y); p[2]=(short)f2bf(x.z); p[3]=(short)f2bf(x.w);
  p[4]=(short)f2bf(y.x); p[5]=(short)f2bf(y.y); p[6]=(short)f2bf(y.z); p[7]=(short)f2bf(y.w);
  *(short8*)(dst+base) = p;
}

// ---------------- P5: wih0[:,300:332] -> f32 [2048][32] ----------------
__global__ __launch_bounds__(256) void p5_wctx(
    const float* __restrict__ wih0, float* __restrict__ ws)
{
  int idx = blockIdx.x*256 + threadIdx.x;
  int j = idx >> 5, d = idx & 31;
  ws[OFF_WCTX + idx] = wih0[(long)j*LIN + En + d];
}

// ---------------- P6: C = sum |v| ----------------
__global__ __launch_bounds__(512) void p6_vc(
    const float* __restrict__ v, float* __restrict__ ws)
{
  __shared__ float s[8];
  int tid = threadIdx.x;
  float a = fabsf(v[tid]);
  #pragma unroll
  for (int m=1;m<64;m<<=1) a += __shfl_xor(a, m, 64);
  if ((tid&63)==0) s[tid>>6] = a;
  __syncthreads();
  if (tid==0){
    float c=0;
    #pragma unroll
    for (int i=0;i<8;i++) c += s[i];
    ws[OFF_VC] = c;
  }
}

// ---------------- P0: zero H2S slot 0 (in out) + flags (in ws) ----------------
__global__ __launch_bounds__(256) void p0_init(float* __restrict__ ws,
                                               float* __restrict__ out){
  int idx = blockIdx.x*256 + threadIdx.x;   // grid 64 -> 16384
  out[O_H2S + idx] = 0.f;
  if (idx < 4352) ws[OFF_FLG + idx] = 0.f;
}

// ---------------- fused 64-step scan: 256 WGs x 256 thr (1 wave/SIMD) ----------------
// Group remap: bg = wg>>6 (contiguous 64-WG groups own a batch-group end to end)
__global__ __launch_bounds__(256, 1)
void scan_all(
    const float* __restrict__ wih1, const float* __restrict__ whh1,
    const float* __restrict__ whh0, const float* __restrict__ bih1,
    const float* __restrict__ bhh1, const float* __restrict__ wh,
    const float* __restrict__ vvec, float* __restrict__ ws,
    float* __restrict__ out)
{
  extern __shared__ float lds[];
  float* hs2  = lds + L_HS2;
  float* hs1  = lds + L_HS1;
  float* gl   = lds + L_GL;
  float* pg0l = lds + L_PG0;
  float* c1l  = lds + L_C1;
  float* c2l  = lds + L_C2;
  float* ctxl = lds + L_CTX;
  float* denl = lds + L_DEN;
  float* ql   = lds + L_QL;
  float* vl   = lds + L_VL;
  float* sp   = lds + L_SP;
  float* esl  = lds + L_ESL;
  float* cp   = lds + L_CP;
  float* w0l  = lds + L_W0;
  float* mkl  = lds + L_MK;
  float* whl  = lds + L_WH;

  const int wg = blockIdx.x, tid = threadIdx.x;
  const int rg = wg & 63, bg = wg >> 6;         // contiguous groups
  const int b2 = wg >> 3, fs = wg & 7;          // P2 identity (within same group)
  const int wv = tid >> 6, L = tid & 63;
  u16* hbf = (u16*)(ws + OFF_HBF);

  // counters: (phase c, group bg) -> FLG index c*4+bg; slots = rg
  const int C_H2 = 0*4+bg, C_Q = 1*4+bg, C_CTX = 2*4+bg, C_H1 = 3*4+bg;

  // ---- persistent per-lane weights: wih1/whh1, 128 VGPR, loaded once ----
  float w_a[8][8], w_b[8][8];
  #pragma unroll
  for (int r=0;r<8;r++){
    int row = wv*512 + rg*8 + r;
    #pragma unroll
    for (int j=0;j<8;j++){
      w_a[r][j] = wih1[(long)row*512 + j*64 + L];
      w_b[r][j] = whh1[(long)row*512 + j*64 + L];
    }
  }
  // ---- whh0 WG rows -> LDS, loaded once ----
  for (int c=0; c<64; c++){
    int idx = c*256 + tid;
    int lr = idx >> 9, k = idx & 511;
    int grow = (lr>>3)*512 + rg*8 + (lr&7);
    w0l[idx] = whh0[(long)grow*512 + k];
  }
  // ---- mkey slice (b2, rows fs*16..fs*16+15) -> LDS, padded ----
  for (int c=0; c<32; c++){
    int idx = c*256 + tid;
    int f = idx >> 9, r = idx & 511;
    mkl[f*528 + (r>>5)*33 + (r&31)] =
        ws[OFF_MKEY + b2*65536 + (fs*16+f)*512 + r];
  }
  // ---- wh rows rg*8..rg*8+7 -> LDS ----
  for (int c=0; c<16; c++){
    int idx = c*256 + tid;
    whl[idx] = wh[(long)(rg*8)*512 + idx];
  }

  // lane redux constants
  const int s4 = ((L&1)<<3) | ((L&2)<<1) | ((L&4)>>1) | ((L&8)>>3);
  const int q_sr = s4 >> 3, q_sx = s4 & 7;
  const int s5 = ((L&1)<<4) | ((L&2)<<2) | (L&4) | ((L&8)>>2) | ((L&16)>>4);
  const int r_sr = s5 >> 3, r_sx = s5 & 7;
  float bsum[2]; int glIdx[2], pgIdx[2];
  #pragma unroll
  for (int p=0;p<2;p++){
    int kk = p*4 + r_sr;
    int row = wv*512 + rg*8 + kk;
    bsum[p] = bih1[row] + bhh1[row];
    glIdx[p] = (wv*8 + kk)*9 + r_sx;
    pgIdx[p] = (wv*8 + kk)*8 + r_sx;
  }

  // ---- persistent LDS init ----
  if (tid < 64){ c1l[tid] = 0.f; c2l[tid] = 0.f; }
  {
    int r = tid>>3, bb = tid&7;
    int row = ((r>>3)<<9) + rg*8 + (r&7);
    pg0l[r*8+bb] = ws[OFF_E0 + bg*16384 + row*8 + bb];
  }
  vl[tid + (tid>>5)] = vvec[tid];
  { int t2 = tid + 256; vl[t2 + (t2>>5)] = vvec[t2]; }
  const float Cv = ws[OFF_VC];
  __syncthreads();

  for (int t=0; t<64; t++){
    const float tgt = (float)(t+1);
    // ================= P1: q = wh @ h2(t-1) =================
    if (t > 0) waitA(ws, C_H2, (float)t, tid);
    {
      const float* h2b = out + O_H2S + t*16384 + bg*4096;
      float4 v0 = *(const float4*)(h2b +    0 + tid*4);
      float4 v1 = *(const float4*)(h2b + 1024 + tid*4);
      float4 v2 = *(const float4*)(h2b + 2048 + tid*4);
      float4 v3 = *(const float4*)(h2b + 3072 + tid*4);
      int kb = tid >> 1, bb0 = (tid&1)*4;
      hs2[(bb0+0)*512 +   0 + kb] = v0.x; hs2[(bb0+1)*512 +   0 + kb] = v0.y;
      hs2[(bb0+2)*512 +   0 + kb] = v0.z; hs2[(bb0+3)*512 +   0 + kb] = v0.w;
      hs2[(bb0+0)*512 + 128 + kb] = v1.x; hs2[(bb0+1)*512 + 128 + kb] = v1.y;
      hs2[(bb0+2)*512 + 128 + kb] = v1.z; hs2[(bb0+3)*512 + 128 + kb] = v1.w;
      hs2[(bb0+0)*512 + 256 + kb] = v2.x; hs2[(bb0+1)*512 + 256 + kb] = v2.y;
      hs2[(bb0+2)*512 + 256 + kb] = v2.z; hs2[(bb0+3)*512 + 256 + kb] = v2.w;
      hs2[(bb0+0)*512 + 384 + kb] = v3.x; hs2[(bb0+1)*512 + 384 + kb] = v3.y;
      hs2[(bb0+2)*512 + 384 + kb] = v3.z; hs2[(bb0+3)*512 + 384 + kb] = v3.w;
    }
    __syncthreads();
    {
      const float* w0p = whl + (wv*2)*512;
      const float* w1p = w0p + 512;
      float vq[16];
      #pragma unroll
      for (int i=0;i<16;i++) vq[i] = 0.f;
      #pragma unroll
      for (int j=0;j<8;j++){
        int k = j*64 + L;
        float wa = w0p[k], wb = w1p[k];
        #pragma unroll
        for (int x=0;x<8;x++){
          float hv = hs2[x*512+k];
          vq[x] += wa*hv; vq[8+x] += wb*hv;
        }
      }
      float qv = redux16(vq, L);
      if (L < 16)
        stc1(out + O_QS + t*16384 + (bg*8+q_sx)*512 + rg*8 + wv*2 + q_sr, qv);
    }
    __syncthreads();
    if (tid == 0) flag_store(ws, C_Q, rg, tgt);

    // ================= P2: scores / exp / ctx-partials =================
    waitA(ws, C_Q, tgt, tid);
    ql[tid + (tid>>5)] = out[O_QS + t*16384 + b2*512 + tid];
    { int t2 = tid + 256; ql[t2 + (t2>>5)] = out[O_QS + t*16384 + b2*512 + t2]; }
    __syncthreads();
    {
      int f = tid>>4, hg = tid&15;
      const float* mkr = mkl + f*528 + hg*33;
      const float* qb = ql + hg*33;
      const float* vb = vl + hg*33;
      float s = 0.f;
      #pragma unroll
      for (int c=0; c<32; c+=4){
        float4 m4 = *(const float4*)(mkr+c);
        s += vb[c+0]*ftanh(qb[c+0]+m4.x) + vb[c+1]*ftanh(qb[c+1]+m4.y)
           + vb[c+2]*ftanh(qb[c+2]+m4.z) + vb[c+3]*ftanh(qb[c+3]+m4.w);
      }
      sp[f*17+hg] = s;
    }
    __syncthreads();
    if (tid < 16){
      float s = 0.f;
      #pragma unroll
      for (int g=0; g<16; g++) s += sp[tid*17+g];
      float e = __expf(s - Cv);
      esl[tid] = e;
      stc1(out + O_ES + t*4096 + b2*128 + fs*16 + tid, e);
    }
    __syncthreads();
    if (tid == 0){
      float d = 0.f;
      #pragma unroll
      for (int i=0;i<16;i++) d += esl[i];
      stc1(out + O_DENP + t*256 + b2*8 + fs, d);
    }
    {
      int d2 = tid&31, f0 = tid>>5;
      cp[d2*17+f0]   = esl[f0]  * ws[OFF_MPROJ + b2*4096 + (fs*16+f0)*32   + d2];
      cp[d2*17+f0+8] = esl[f0+8]* ws[OFF_MPROJ + b2*4096 + (fs*16+f0+8)*32 + d2];
    }
    __syncthreads();
    if (tid < 32){
      float s = 0.f;
      #pragma unroll
      for (int ff=0; ff<16; ff++) s += cp[tid*17+ff];
      stc1(out + O_CTXP + t*8192 + b2*256 + fs*32 + tid, s);
    }
    __syncthreads();
    if (tid == 0) flag_store(ws, C_CTX, rg, tgt);

    // ================= P3: ctx gather + gates0 + cell1 =================
    waitA(ws, C_CTX, tgt, tid);
    if (tid < 8){
      float dsum = 0.f;
      #pragma unroll
      for (int f2=0; f2<8; f2++) dsum += out[O_DENP + t*256 + (bg*8+tid)*8 + f2];
      denl[tid] = frcp(dsum);
    }
    __syncthreads();
    {
      int bb = tid>>5, d = tid&31;
      float s = 0.f;
      #pragma unroll
      for (int f2=0; f2<8; f2++) s += out[O_CTXP + t*8192 + (bg*8+bb)*256 + f2*32 + d];
      ctxl[bb*33+d] = s * denl[bb];
    }
    if (rg == 0){
      #pragma unroll
      for (int i0=0; i0<4; i0++){
        int i = tid + i0*256;
        int bb = i>>7, f = i&127;
        float e = out[O_ES + t*4096 + (bg*8+bb)*128 + f];
        __builtin_nontemporal_store(e * denl[bb],
            out + OUT_ATT + (bg*8+bb)*8192 + t*128 + f);
      }
    }
    __syncthreads();
    {
      int r = tid>>3, bb = tid&7;
      int row = ((r>>3)<<9) + rg*8 + (r&7);
      float g0 = pg0l[r*8+bb];
      const float* wr = ws + OFF_WCTX + row*32;
      #pragma unroll
      for (int d2=0; d2<32; d2+=4){
        float4 w4 = *(const float4*)(wr+d2);
        g0 += w4.x*ctxl[bb*33+d2] + w4.y*ctxl[bb*33+d2+1]
            + w4.z*ctxl[bb*33+d2+2] + w4.w*ctxl[bb*33+d2+3];
      }
      gl[r*9+bb] = g0;
    }
    __syncthreads();
    if (tid < 64){
      int kk = tid>>3, bb = tid&7;
      float gi = gl[(kk)*9+bb],     gf = gl[(8+kk)*9+bb];
      float gg2 = gl[(16+kk)*9+bb], go = gl[(24+kk)*9+bb];
      float cp2 = c1l[tid];
      float cn = fsig(gf)*cp2 + fsig(gi)*ftanh(gg2);
      float hn = fsig(go)*ftanh(cn);
      c1l[tid] = cn;
      stc1(out + O_H1S + t*16384 + bg*4096 + (rg*8+kk)*8 + bb, hn);
      if (t == 63){
        int bgl = bg*8+bb, kgl = rg*8+kk;
        __builtin_nontemporal_store(hn, out + OUT_HF + bgl*512 + kgl);
        __builtin_nontemporal_store(cn, out + OUT_CF + bgl*512 + kgl);
      }
    }
    __syncthreads();
    if (tid == 0) flag_store(ws, C_H1, rg, tgt);

    // ================= P4: gates1 + cell2 (+ pg0(t+1) off critical path) ======
    waitA(ws, C_H1, tgt, tid);
    {
      const float* h1b = out + O_H1S + t*16384 + bg*4096;
      float4 v0 = *(const float4*)(h1b +    0 + tid*4);
      float4 v1 = *(const float4*)(h1b + 1024 + tid*4);
      float4 v2 = *(const float4*)(h1b + 2048 + tid*4);
      float4 v3 = *(const float4*)(h1b + 3072 + tid*4);
      int kb = tid >> 1, bb0 = (tid&1)*4;
      hs1[(bb0+0)*512 +   0 + kb] = v0.x; hs1[(bb0+1)*512 +   0 + kb] = v0.y;
      hs1[(bb0+2)*512 +   0 + kb] = v0.z; hs1[(bb0+3)*512 +   0 + kb] = v0.w;
      hs1[(bb0+0)*512 + 128 + kb] = v1.x; hs1[(bb0+1)*512 + 128 + kb] = v1.y;
      hs1[(bb0+2)*512 + 128 + kb] = v1.z; hs1[(bb0+3)*512 + 128 + kb] = v1.w;
      hs1[(bb0+0)*512 + 256 + kb] = v2.x; hs1[(bb0+1)*512 + 256 + kb] = v2.y;
      hs1[(bb0+2)*512 + 256 + kb] = v2.z; hs1[(bb0+3)*512 + 256 + kb] = v2.w;
      hs1[(bb0+0)*512 + 384 + kb] = v3.x; hs1[(bb0+1)*512 + 384 + kb] = v3.y;
      hs1[(bb0+2)*512 + 384 + kb] = v3.z; hs1[(bb0+3)*512 + 384 + kb] = v3.w;
    }
    __syncthreads();
    #pragma unroll
    for (int p=0; p<2; p++){
      float vals[32];
      #pragma unroll
      for (int i=0;i<32;i++) vals[i] = 0.f;
      #pragma unroll
      for (int j=0;j<8;j++){
        int k = j*64 + L;
        float h1v[8], h2v[8];
        #pragma unroll
        for (int x=0;x<8;x++){ h1v[x] = hs1[x*512+k]; h2v[x] = hs2[x*512+k]; }
        #pragma unroll
        for (int r=0;r<4;r++){
          const float wa = w_a[p*4+r][j], wb = w_b[p*4+r][j];
          #pragma unroll
          for (int x=0;x<8;x++) vals[r*8+x] += wa*h1v[x] + wb*h2v[x];
        }
      }
      float v0 = redux32(vals, L);
      if (L < 32) gl[glIdx[p]] = v0 + bsum[p];
    }
    __syncthreads();
    if (tid < 64){
      int kk = tid>>3, bb = tid&7;
      float gi = gl[(kk)*9+bb],     gf = gl[(8+kk)*9+bb];
      float gg2 = gl[(16+kk)*9+bb], go = gl[(24+kk)*9+bb];
      float cp3 = c2l[tid];
      float cn = fsig(gf)*cp3 + fsig(gi)*ftanh(gg2);
      float hn = fsig(go)*ftanh(cn);
      c2l[tid] = cn;
      int k2 = rg*8+kk, b = bg*8+bb;
      stc1(out + O_H2S + (t+1)*16384 + bg*4096 + k2*8 + bb, hn);
      __builtin_nontemporal_store(f2bf(hn), hbf + (t*32+b)*512 + k2);
      if (t == 63){
        __builtin_nontemporal_store(hn, out + OUT_HF + 16384 + b*512 + k2);
        __builtin_nontemporal_store(cn, out + OUT_CF + 16384 + b*512 + k2);
      }
    }
    __syncthreads();                 // drains h2 stores before signal
    if (tid == 0) flag_store(ws, C_H2, rg, tgt);

    // pg0(t+1) = whh0 @ h1 (+ E0[t+1]) — whh0 in LDS, WG-local consumer
    if (t < 63){
      #pragma unroll
      for (int p=0; p<2; p++){
        float vals[32];
        #pragma unroll
        for (int i=0;i<32;i++) vals[i] = 0.f;
        #pragma unroll
        for (int j=0;j<8;j++){
          int k = j*64 + L;
          float h1v[8];
          #pragma unroll
          for (int x=0;x<8;x++) h1v[x] = hs1[x*512+k];
          #pragma unroll
          for (int r=0;r<4;r++){
            const float wc = w0l[(wv*8 + p*4 + r)*512 + k];
            #pragma unroll
            for (int x=0;x<8;x++) vals[r*8+x] += wc*h1v[x];
          }
        }
        float v0 = redux32(vals, L);
        if (L < 32) pg0l[pgIdx[p]] = v0;
      }
      __syncthreads();
      {
        int r = tid>>3, bb = tid&7;
        int row = ((r>>3)<<9) + rg*8 + (r&7);
        pg0l[r*8+bb] += __builtin_nontemporal_load(
            ws + OFF_E0 + (t+1)*65536 + bg*16384 + row*8 + bb);
      }
    }
    // loop-top waitA's __syncthreads orders pg0l for next P3
  }
}

// ---------------- FC: logits = h @ fc_w^T + fc_b (bf16 MFMA) ----------------
__global__ __launch_bounds__(256) void fc_gemm(
    const float* __restrict__ ws_f, const float* __restrict__ fcb,
    float* __restrict__ out)
{
  const u16* A  = (const u16*)(ws_f + OFF_FCWBF);
  const u16* Bm = (const u16*)(ws_f + OFF_HBF);
  __shared__ u16 Al[128*40];
  __shared__ u16 Bl[128*40];
  int tid = threadIdx.x;
  int v0 = blockIdx.x*128, bt0 = blockIdx.y*128;
  int lane = tid & 63, wv = tid >> 6;
  int wr = wv >> 1, wc = wv & 1;
  f32x4 acc[4][4];
  #pragma unroll
  for (int i=0;i<4;i++)
    #pragma unroll
    for (int j=0;j<4;j++) acc[i][j] = (f32x4){0.f,0.f,0.f,0.f};

  int ar = wr*64 + (lane&15);
  int br = wc*64 + (lane&15);
  int ks = (lane>>4)*8;

  for (int kk=0; kk<512; kk+=32){
    __syncthreads();
    #pragma unroll
    for (int i=0;i<2;i++){
      int ld = tid + 256*i;
      int row = ld >> 2, cs = (ld & 3)*8;
      *(int4*)(&Al[row*40+cs]) = *(const int4*)(A  + (v0+row)*512 + kk + cs);
      *(int4*)(&Bl[row*40+cs]) = *(const int4*)(Bm + (bt0+row)*512 + kk + cs);
    }
    __syncthreads();
    short8 af[4], bf[4];
    #pragma unroll
    for (int m=0;m<4;m++) af[m] = *(const short8*)(&Al[(ar+m*16)*40 + ks]);
    #pragma unroll
    for (int n=0;n<4;n++) bf[n] = *(const short8*)(&Bl[(br+n*16)*40 + ks]);
    #pragma unroll
    for (int m=0;m<4;m++)
      #pragma unroll
      for (int n=0;n<4;n++)
        acc[m][n] = __builtin_amdgcn_mfma_f32_16x16x32_bf16(af[m], bf[n], acc[m][n], 0,0,0);
  }
  int r4 = (lane>>4)*4;
  #pragma unroll
  for (int m=0;m<4;m++){
    int v = v0 + wr*64 + m*16 + r4;
    float4 bias = *(const float4*)(fcb + v);
    #pragma unroll
    for (int n=0;n<4;n++){
      int bt = bt0 + wc*64 + n*16 + (lane&15);
      int b = bt & 31, t = bt >> 5;
      f32x4 a = acc[m][n];
      float4 res = { a[0]+bias.x, a[1]+bias.y, a[2]+bias.z, a[3]+bias.w };
      *(float4*)(out + b*2048000 + t*32000 + v) = res;
    }
  }
}

extern "C" void kernel_launch(void* const* d_in, const int* in_sizes, int n_in,
                              void* d_out, int out_size, void* d_ws, size_t ws_size,
                              hipStream_t stream)
{
  const int*   seq  = (const int*)d_in[0];
  const float* midi = (const float*)d_in[1];
  const float* emb  = (const float*)d_in[2];
  const float* mpw  = (const float*)d_in[3];
  const float* mpb  = (const float*)d_in[4];
  const float* wh   = (const float*)d_in[5];
  const float* wm   = (const float*)d_in[6];
  const float* vv   = (const float*)d_in[7];
  const float* wih0 = (const float*)d_in[8];
  const float* whh0 = (const float*)d_in[9];
  const float* bih0 = (const float*)d_in[10];
  const float* bhh0 = (const float*)d_in[11];
  const float* wih1 = (const float*)d_in[12];
  const float* whh1 = (const float*)d_in[13];
  const float* bih1 = (const float*)d_in[14];
  const float* bhh1 = (const float*)d_in[15];
  const float* fcw  = (const float*)d_in[16];
  const float* fcb  = (const float*)d_in[17];
  float* out = (float*)d_out;
  float* ws  = (float*)d_ws;

  hipFuncSetAttribute((const void*)scan_all,
                      hipFuncAttributeMaxDynamicSharedMemorySize,
                      SCAN_LDS_BYTES);

  p1_midi<<<32, 1024, 0, stream>>>(midi, mpw, mpb, wm, ws);
  p2a_x  <<<640, 256, 0, stream>>>(seq, emb, ws);
  p2b_w  <<<640, 256, 0, stream>>>(wih0, ws);
  p2c_e0 <<<dim3(16,16), 256, 0, stream>>>(ws, bih0, bhh0, ws);
  p3_cvt <<<8000, 256, 0, stream>>>(fcw, ws);
  p5_wctx<<<256, 256, 0, stream>>>(wih0, ws);
  p6_vc  <<<1, 512, 0, stream>>>(vv, ws);
  p0_init<<<64, 256, 0, stream>>>(ws, out);

  scan_all<<<NWG, 256, SCAN_LDS_BYTES, stream>>>(wih1, whh1, whh0, bih1, bhh1,
                                                 wh, vv, ws, out);

  fc_gemm<<<dim3(250,16), 256, 0, stream>>>(ws, fcb, out);
}

// Round 19
// 4959.669 us; speedup vs baseline: 1.1471x; 1.1175x over previous
//
#include <hip/hip_runtime.h>
#include <hip/hip_bf16.h>

#define Bsz 32
#define Tn  64
#define Vn  32000
#define En  300
#define Hn  512
#define NFn 128
#define Dn  32
#define G4  2048
#define LIN 332
#define NWG 256

// workspace offsets (float units)
#define OFF_MPROJ 0
#define OFF_E0    (OFF_MPROJ + 131072)     /* fp32 [64][4 bg][2048][8] */
#define OFF_PG0B  (OFF_E0 + 4194304)
#define OFF_H1T   (OFF_PG0B + 65536)
#define OFF_H2T0  (OFF_H1T + 16384)
#define OFF_H2T1  (OFF_H2T0 + 16384)
#define OFF_H2BB  (OFF_H2T1 + 16384)
#define OFF_C1T   (OFF_H2BB + 16384)
#define OFF_C2T   (OFF_C1T + 16384)
#define OFF_FLG   (OFF_C2T + 16384)        /* 16 ctr x 64 slots x 4 floats */
#define OFF_DONE  (OFF_FLG + 4096)
#define OFF_VC    (OFF_DONE + 256)
#define OFF_MKEY  (OFF_VC + 16)            /* fp32 [32][128][512] */
#define OFF_WHT   (OFF_MKEY + 2097152)
#define OFF_WCTX  (OFF_WHT + 262144)       /* fp32 [2048][32] */
#define OFF_X     (OFF_WCTX + 65536)
#define OFF_W0    (OFF_X + 655360)
#define OFF_HBF   OFF_X                    /* bf16 [2048][512] */
#define OFF_FCWBF (OFF_X + 524288)         /* bf16 [32000][512] */

// step-unique buffers in the LOGITS region of d_out
#define O_H1S  0
#define O_H2S  1048576
#define O_QS   2113536
#define O_CTXP 3162112
#define O_DENP 3686400
#define O_ES   3702784

// output offsets (float units)
#define OUT_HF  65536000
#define OUT_CF  65568768
#define OUT_ATT 65601536

// scan LDS map (floats) — sp widened to [16][33]
#define L_HS2   0        /* [8][512] */
#define L_HS1   4096     /* [8][512] */
#define L_GL    8192     /* [32][9]  */
#define L_PG0   8480     /* [32][8]  */
#define L_C1    8736     /* [64]     */
#define L_C2    8800     /* [64]     */
#define L_CTX   8864     /* [8][33]  */
#define L_DEN   9128     /* [8]      */
#define L_QL    9136     /* [528]    */
#define L_VL    9664     /* [528]    */
#define L_SP    10192    /* [16][33] = 528 */
#define L_ESL   10720    /* [16]     */
#define L_CP    10736    /* [32][17] */
#define L_W0    11280    /* [32][512] whh0 WG rows */
#define L_MK    27664    /* [16][16*33] mkey slice (padded) */
#define L_WH    36112    /* [8][512] wh WG rows */
#define SCAN_LDS_FLOATS 40208
#define SCAN_LDS_BYTES  (SCAN_LDS_FLOATS*4)   /* 160832 B <= 160 KiB */

typedef __attribute__((ext_vector_type(8))) short short8;
typedef __attribute__((ext_vector_type(4))) float f32x4;
typedef unsigned short u16;

__device__ __forceinline__ float frcp(float x){ return __builtin_amdgcn_rcpf(x); }
__device__ __forceinline__ float ftanh(float x){
  float e = __expf(2.0f*x);
  return 1.0f - 2.0f*frcp(e+1.0f);
}
__device__ __forceinline__ float fsig(float x){
  return frcp(1.0f + __expf(-x));
}
__device__ __forceinline__ u16 f2bf(float f){
  __hip_bfloat16 h = __float2bfloat16(f);
  u16 r; __builtin_memcpy(&r, &h, 2); return r;
}

__device__ __forceinline__ float ldc1(const float* p){
  return __hip_atomic_load(p, __ATOMIC_RELAXED, __HIP_MEMORY_SCOPE_AGENT);
}
__device__ __forceinline__ void stc1(float* p, float v){
  __hip_atomic_store(p, v, __ATOMIC_RELAXED, __HIP_MEMORY_SCOPE_AGENT);
}

// ---- direct group barrier (R18-verified) ----
__device__ __forceinline__ void flag_store(float* ws, int c, int slot, float v){
  stc1(ws + OFF_FLG + c*256 + slot*4, v);
}
__device__ __forceinline__ void waitA(float* ws, int c, float tgt, int tid){
  __syncthreads();
  if (tid < 64){
    const float* fl = ws + OFF_FLG + c*256;
    unsigned cc = 0;
    while (true){
      float v = ldc1(fl + tid*4);
      if (__ballot(v >= tgt) == ~0ull) break;
      if (++cc >= (1u<<22)) break;   // terminate rather than hang
    }
  }
  __syncthreads();
  asm volatile("" ::: "memory");
}

// 32-value reduce-scatter over 64 lanes; owner slot = bitrev5(L&31) for L<32.
__device__ __forceinline__ float redux32(float (&v)[32], int L){
  #pragma unroll
  for (int i=0;i<5;i++){
    const int m = 1<<i, h = 16>>i;
    const bool up = (L & m);
    #pragma unroll
    for (int u=0; u<h; u++){
      float send = up ? v[u] : v[u+h];
      float keep = up ? v[u+h] : v[u];
      v[u] = keep + __shfl_xor(send, m, 64);
    }
  }
  v[0] += __shfl_xor(v[0], 32, 64);
  return v[0];
}
// 8-value version: slot = bitrev3(L&7) for L<8
__device__ __forceinline__ float redux8(float (&v)[8], int L){
  #pragma unroll
  for (int i=0;i<3;i++){
    const int m = 1<<i, h = 4>>i;
    const bool up = (L & m);
    #pragma unroll
    for (int u=0; u<h; u++){
      float send = up ? v[u] : v[u+h];
      float keep = up ? v[u+h] : v[u];
      v[u] = keep + __shfl_xor(send, m, 64);
    }
  }
  v[0] += __shfl_xor(v[0], 8, 64);
  v[0] += __shfl_xor(v[0], 16, 64);
  v[0] += __shfl_xor(v[0], 32, 64);
  return v[0];
}

// ---------------- P1: midi_proj (f32) + midi_key (f32) ----------------
__global__ __launch_bounds__(1024) void p1_midi(
    const float* __restrict__ midi, const float* __restrict__ mp_w,
    const float* __restrict__ mp_b, const float* __restrict__ wm,
    float* __restrict__ ws)
{
  __shared__ float ms[NFn*Dn];
  __shared__ float pj[NFn*33];
  __shared__ float mpw[Dn*33];
  __shared__ float mpb[Dn];
  int b = blockIdx.x, tid = threadIdx.x;
  for (int i=tid;i<NFn*Dn;i+=1024) ms[i] = midi[b*NFn*Dn + i];
  { int e = tid>>5, d = tid&31; mpw[e*33+d] = mp_w[tid]; }
  if (tid < Dn) mpb[tid] = mp_b[tid];
  __syncthreads();
  float* mproj = ws + OFF_MPROJ;
  for (int i=tid;i<NFn*Dn;i+=1024){
    int f = i>>5, e = i&31;
    float a = mpb[e];
    #pragma unroll
    for (int d=0;d<Dn;d++) a += ms[f*32+d]*mpw[e*33+d];
    a = fmaxf(a, 0.0f);
    pj[f*33+e] = a;
    mproj[b*NFn*Dn + i] = a;
  }
  __syncthreads();
  int h = tid & 511, fh = tid >> 9;
  float wreg[32];
  #pragma unroll
  for (int d=0;d<32;d++) wreg[d] = wm[h*32+d];
  float* mkf = ws + OFF_MKEY + b*(NFn*Hn);
  for (int ff=0; ff<64; ff++){
    int f = fh*64 + ff;
    float a = 0.f;
    #pragma unroll
    for (int d=0;d<32;d++) a += pj[f*33+d]*wreg[d];
    mkf[f*512 + h] = a;
  }
}

// ---------------- P2a: gather embeddings -> f32 X[2048][320] ----------------
__global__ __launch_bounds__(256) void p2a_x(
    const int* __restrict__ seq, const float* __restrict__ emb,
    float* __restrict__ ws)
{
  int idx = blockIdx.x*256 + threadIdx.x;
  int bt = idx / 80, c4 = idx - bt*80;
  int b = bt & 31, t = bt >> 5;
  float4 x = {0.f,0.f,0.f,0.f};
  if (c4 < 75){
    int s = seq[b*Tn + t];
    x = *(const float4*)(emb + (long)s*En + c4*4);
  }
  *(float4*)(ws + OFF_X + bt*320 + c4*4) = x;
}

// ---------------- P2b: wih0[:, :300] -> f32 [2048][320] padded ----------------
__global__ __launch_bounds__(256) void p2b_w(
    const float* __restrict__ wih0, float* __restrict__ ws)
{
  int idx = blockIdx.x*256 + threadIdx.x;
  int j = idx / 80, c4 = idx - j*80;
  float4 x = {0.f,0.f,0.f,0.f};
  if (c4 < 75) x = *(const float4*)(wih0 + (long)j*LIN + c4*4);
  *(float4*)(ws + OFF_W0 + j*320 + c4*4) = x;
}

// ---------------- P2c: E0 = W0 @ X^T + bias (fp32 SGEMM) ----------------
__global__ __launch_bounds__(256) void p2c_e0(
    const float* __restrict__ ws_c, const float* __restrict__ bih0,
    const float* __restrict__ bhh0, float* __restrict__ ws)
{
  const float* A  = ws_c + OFF_W0;
  const float* Bm = ws_c + OFF_X;
  __shared__ float Al[32][132];
  __shared__ float Bl[32][132];
  int tid = threadIdx.x;
  int j0t = blockIdx.x*128, bt0 = blockIdx.y*128;
  int tx = tid & 15, ty = tid >> 4;
  float acc[8][8];
  #pragma unroll
  for (int i=0;i<8;i++)
    #pragma unroll
    for (int j=0;j<8;j++) acc[i][j] = 0.f;

  int m = tid >> 1;
  int kq = (tid & 1) * 16;
  for (int kk=0; kk<320; kk+=32){
    __syncthreads();
    {
      const float* As = A  + (long)(j0t+m)*320 + kk + kq;
      const float* Bs = Bm + (long)(bt0+m)*320 + kk + kq;
      float4 a0 = *(const float4*)(As+0), a1 = *(const float4*)(As+4);
      float4 a2 = *(const float4*)(As+8), a3 = *(const float4*)(As+12);
      float4 b0 = *(const float4*)(Bs+0), b1 = *(const float4*)(Bs+4);
      float4 b2 = *(const float4*)(Bs+8), b3 = *(const float4*)(Bs+12);
      Al[kq+0][m]=a0.x; Al[kq+1][m]=a0.y; Al[kq+2][m]=a0.z; Al[kq+3][m]=a0.w;
      Al[kq+4][m]=a1.x; Al[kq+5][m]=a1.y; Al[kq+6][m]=a1.z; Al[kq+7][m]=a1.w;
      Al[kq+8][m]=a2.x; Al[kq+9][m]=a2.y; Al[kq+10][m]=a2.z; Al[kq+11][m]=a2.w;
      Al[kq+12][m]=a3.x; Al[kq+13][m]=a3.y; Al[kq+14][m]=a3.z; Al[kq+15][m]=a3.w;
      Bl[kq+0][m]=b0.x; Bl[kq+1][m]=b0.y; Bl[kq+2][m]=b0.z; Bl[kq+3][m]=b0.w;
      Bl[kq+4][m]=b1.x; Bl[kq+5][m]=b1.y; Bl[kq+6][m]=b1.z; Bl[kq+7][m]=b1.w;
      Bl[kq+8][m]=b2.x; Bl[kq+9][m]=b2.y; Bl[kq+10][m]=b2.z; Bl[kq+11][m]=b2.w;
      Bl[kq+12][m]=b3.x; Bl[kq+13][m]=b3.y; Bl[kq+14][m]=b3.z; Bl[kq+15][m]=b3.w;
    }
    __syncthreads();
    #pragma unroll 4
    for (int k=0;k<32;k++){
      float4 a0 = *(const float4*)&Al[k][ty*8];
      float4 a1 = *(const float4*)&Al[k][ty*8+4];
      float4 b0 = *(const float4*)&Bl[k][tx*8];
      float4 b1 = *(const float4*)&Bl[k][tx*8+4];
      float av[8] = {a0.x,a0.y,a0.z,a0.w,a1.x,a1.y,a1.z,a1.w};
      float bv[8] = {b0.x,b0.y,b0.z,b0.w,b1.x,b1.y,b1.z,b1.w};
      #pragma unroll
      for (int i=0;i<8;i++)
        #pragma unroll
        for (int j=0;j<8;j++) acc[i][j] += av[i]*bv[j];
    }
  }
  float* E0 = ws + OFF_E0;
  #pragma unroll
  for (int i=0;i<8;i++){
    int j = j0t + ty*8 + i;
    float be = bih0[j] + bhh0[j];
    #pragma unroll
    for (int jj=0;jj<8;jj++){
      int c = bt0 + tx*8 + jj;
      int tt = c >> 5, bb = c & 31;
      E0[tt*65536 + (bb>>3)*16384 + j*8 + (bb&7)] = acc[i][jj] + be;
    }
  }
}

// ---------------- P3: fc_w -> bf16 ----------------
__global__ __launch_bounds__(256) void p3_cvt(
    const float* __restrict__ fcw, float* __restrict__ ws)
{
  u16* dst = (u16*)(ws + OFF_FCWBF);
  int base = (blockIdx.x*256 + threadIdx.x)*8;
  float4 x = *(const float4*)(fcw+base);
  float4 y = *(const float4*)(fcw+base+4);
  short8 p;
  p[0]=(short)f2bf(x.x); p[1]=(short)f2bf(x.y); p[2]=(short)f2bf(x.z); p[3]=(short)f2bf(x.w);
  p[4]=(short)f2bf(y.x); p[5]=(short)f2bf(y.y); p[6]=(short)f2bf(y.z); p[7]=(short)f2bf(y.w);
  *(short8*)(dst+base) = p;
}

// ---------------- P5: wih0[:,300:332] -> f32 [2048][32] ----------------
__global__ __launch_bounds__(256) void p5_wctx(
    const float* __restrict__ wih0, float* __restrict__ ws)
{
  int idx = blockIdx.x*256 + threadIdx.x;
  int j = idx >> 5, d = idx & 31;
  ws[OFF_WCTX + idx] = wih0[(long)j*LIN + En + d];
}

// ---------------- P6: C = sum |v| ----------------
__global__ __launch_bounds__(512) void p6_vc(
    const float* __restrict__ v, float* __restrict__ ws)
{
  __shared__ float s[8];
  int tid = threadIdx.x;
  float a = fabsf(v[tid]);
  #pragma unroll
  for (int m=1;m<64;m<<=1) a += __shfl_xor(a, m, 64);
  if ((tid&63)==0) s[tid>>6] = a;
  __syncthreads();
  if (tid==0){
    float c=0;
    #pragma unroll
    for (int i=0;i<8;i++) c += s[i];
    ws[OFF_VC] = c;
  }
}

// ---------------- P0: zero H2S slot 0 (in out) + flags (in ws) ----------------
__global__ __launch_bounds__(256) void p0_init(float* __restrict__ ws,
                                               float* __restrict__ out){
  int idx = blockIdx.x*256 + threadIdx.x;   // grid 64 -> 16384
  out[O_H2S + idx] = 0.f;
  if (idx < 4352) ws[OFF_FLG + idx] = 0.f;
}

// ---------------- fused 64-step scan: 256 WGs x 512 thr (2 waves/SIMD) ----------------
__global__ __launch_bounds__(512, 1)
void scan_all(
    const float* __restrict__ wih1, const float* __restrict__ whh1,
    const float* __restrict__ whh0, const float* __restrict__ bih1,
    const float* __restrict__ bhh1, const float* __restrict__ wh,
    const float* __restrict__ vvec, float* __restrict__ ws,
    float* __restrict__ out)
{
  extern __shared__ float lds[];
  float* hs2  = lds + L_HS2;
  float* hs1  = lds + L_HS1;
  float* gl   = lds + L_GL;
  float* pg0l = lds + L_PG0;
  float* c1l  = lds + L_C1;
  float* c2l  = lds + L_C2;
  float* ctxl = lds + L_CTX;
  float* denl = lds + L_DEN;
  float* ql   = lds + L_QL;
  float* vl   = lds + L_VL;
  float* sp   = lds + L_SP;    // [16][33]
  float* esl  = lds + L_ESL;
  float* cp   = lds + L_CP;
  float* w0l  = lds + L_W0;
  float* mkl  = lds + L_MK;
  float* whl  = lds + L_WH;

  const int wg = blockIdx.x, tid = threadIdx.x;
  const int rg = wg & 63, bg = wg >> 6;         // contiguous groups (R18)
  const int b2 = wg >> 3, fs = wg & 7;
  const int W = tid >> 6, L = tid & 63;         // 8 waves
  u16* hbf = (u16*)(ws + OFF_HBF);

  const int C_H2 = 0*4+bg, C_Q = 1*4+bg, C_CTX = 2*4+bg, C_H1 = 3*4+bg;

  // ---- persistent per-lane weights: wave W owns 4 local rows W*4..W*4+3 ----
  float w_a[4][8], w_b[4][8];
  #pragma unroll
  for (int r=0;r<4;r++){
    int lr = W*4 + r;
    int row = ((lr>>3)<<9) + rg*8 + (lr&7);
    #pragma unroll
    for (int j=0;j<8;j++){
      w_a[r][j] = wih1[(long)row*512 + j*64 + L];
      w_b[r][j] = whh1[(long)row*512 + j*64 + L];
    }
  }
  // ---- whh0 WG rows -> LDS ----
  for (int c=0; c<32; c++){
    int idx = c*512 + tid;
    int lr = idx >> 9, k = idx & 511;
    int grow = (lr>>3)*512 + rg*8 + (lr&7);
    w0l[idx] = whh0[(long)grow*512 + k];
  }
  // ---- mkey slice -> LDS (padded) ----
  for (int c=0; c<16; c++){
    int idx = c*512 + tid;
    int f = idx >> 9, r = idx & 511;
    mkl[f*528 + (r>>5)*33 + (r&31)] =
        ws[OFF_MKEY + b2*65536 + (fs*16+f)*512 + r];
  }
  // ---- wh rows -> LDS ----
  for (int c=0; c<8; c++){
    int idx = c*512 + tid;
    whl[idx] = wh[(long)(rg*8)*512 + idx];
  }

  // lane redux constants
  const int s5 = ((L&1)<<4) | ((L&2)<<2) | (L&4) | ((L&8)>>2) | ((L&16)>>4);
  const int r_sr = s5 >> 3, r_sx = s5 & 7;     // redux32 owner (L<32)
  const int lr_g = W*4 + r_sr;
  const int row_g = ((lr_g>>3)<<9) + rg*8 + (lr_g&7);
  const float bsum = bih1[row_g] + bhh1[row_g];
  const int glIdx = lr_g*9 + r_sx;
  const int pgIdx = lr_g*8 + r_sx;
  const int brev = ((L&1)<<2) | (L&2) | ((L>>2)&1);   // redux8 owner (L<8)

  // ---- persistent LDS init ----
  if (tid < 64){ c1l[tid] = 0.f; c2l[tid] = 0.f; }
  if (tid < 256){
    int r = tid>>3, bb = tid&7;
    int row = ((r>>3)<<9) + rg*8 + (r&7);
    pg0l[r*8+bb] = ws[OFF_E0 + bg*16384 + row*8 + bb];
  }
  vl[tid + (tid>>5)] = vvec[tid];
  const float Cv = ws[OFF_VC];
  __syncthreads();

  for (int t=0; t<64; t++){
    const float tgt = (float)(t+1);
    // ================= P1: q = wh @ h2(t-1) =================
    if (t > 0) waitA(ws, C_H2, (float)t, tid);
    {
      const float* h2b = out + O_H2S + t*16384 + bg*4096;
      #pragma unroll
      for (int c=0;c<2;c++){
        int i = c*512 + tid;
        float4 v = *(const float4*)(h2b + i*4);
        int k = i>>1, bb0 = (i&1)*4;
        hs2[(bb0+0)*512+k]=v.x; hs2[(bb0+1)*512+k]=v.y;
        hs2[(bb0+2)*512+k]=v.z; hs2[(bb0+3)*512+k]=v.w;
      }
    }
    __syncthreads();
    {
      const float* w0p = whl + W*512;   // wave W owns q-row rg*8+W
      float vq[8];
      #pragma unroll
      for (int i=0;i<8;i++) vq[i] = 0.f;
      #pragma unroll
      for (int j=0;j<8;j++){
        int k = j*64 + L;
        float wa = w0p[k];
        #pragma unroll
        for (int x=0;x<8;x++) vq[x] += wa*hs2[x*512+k];
      }
      float qv = redux8(vq, L);
      if (L < 8)
        stc1(out + O_QS + t*16384 + (bg*8+brev)*512 + rg*8 + W, qv);
    }
    __syncthreads();
    if (tid == 0) flag_store(ws, C_Q, rg, tgt);

    // ================= P2: scores / exp / ctx-partials =================
    waitA(ws, C_Q, tgt, tid);
    ql[tid + (tid>>5)] = out[O_QS + t*16384 + b2*512 + tid];
    __syncthreads();
    {
      int f = tid>>5, hg = tid&31;     // 32 threads per f, 16 h each
      int base = (hg>>1)*33 + (hg&1)*16;
      const float* mkr = mkl + f*528 + base;
      const float* qb = ql + base;
      const float* vb = vl + base;
      float s = 0.f;
      #pragma unroll
      for (int c=0; c<16; c+=4){
        float4 m4 = *(const float4*)(mkr+c);
        s += vb[c+0]*ftanh(qb[c+0]+m4.x) + vb[c+1]*ftanh(qb[c+1]+m4.y)
           + vb[c+2]*ftanh(qb[c+2]+m4.z) + vb[c+3]*ftanh(qb[c+3]+m4.w);
      }
      sp[f*33+hg] = s;
    }
    __syncthreads();
    if (tid < 16){
      float s = 0.f;
      #pragma unroll
      for (int g=0; g<32; g++) s += sp[tid*33+g];
      float e = __expf(s - Cv);
      esl[tid] = e;
      stc1(out + O_ES + t*4096 + b2*128 + fs*16 + tid, e);
    }
    __syncthreads();
    if (tid == 0){
      float d = 0.f;
      #pragma unroll
      for (int i=0;i<16;i++) d += esl[i];
      stc1(out + O_DENP + t*256 + b2*8 + fs, d);
    }
    {
      int d2 = tid&31, f0 = tid>>5;    // 512 threads: one (d,f) each
      cp[d2*17+f0] = esl[f0] * ws[OFF_MPROJ + b2*4096 + (fs*16+f0)*32 + d2];
    }
    __syncthreads();
    if (tid < 32){
      float s = 0.f;
      #pragma unroll
      for (int ff=0; ff<16; ff++) s += cp[tid*17+ff];
      stc1(out + O_CTXP + t*8192 + b2*256 + fs*32 + tid, s);
    }
    __syncthreads();
    if (tid == 0) flag_store(ws, C_CTX, rg, tgt);

    // ================= P3: ctx gather + gates0 + cell1 =================
    waitA(ws, C_CTX, tgt, tid);
    if (tid < 8){
      float dsum = 0.f;
      #pragma unroll
      for (int f2=0; f2<8; f2++) dsum += out[O_DENP + t*256 + (bg*8+tid)*8 + f2];
      denl[tid] = frcp(dsum);
    }
    __syncthreads();
    if (tid < 256){
      int bb = tid>>5, d = tid&31;
      float s = 0.f;
      #pragma unroll
      for (int f2=0; f2<8; f2++) s += out[O_CTXP + t*8192 + (bg*8+bb)*256 + f2*32 + d];
      ctxl[bb*33+d] = s * denl[bb];
    }
    if (rg == 0){
      #pragma unroll
      for (int i0=0; i0<2; i0++){
        int i = tid + i0*512;
        int bb = i>>7, f = i&127;
        float e = out[O_ES + t*4096 + (bg*8+bb)*128 + f];
        __builtin_nontemporal_store(e * denl[bb],
            out + OUT_ATT + (bg*8+bb)*8192 + t*128 + f);
      }
    }
    __syncthreads();
    if (tid < 256){
      int r = tid>>3, bb = tid&7;
      int row = ((r>>3)<<9) + rg*8 + (r&7);
      float g0 = pg0l[r*8+bb];
      const float* wr = ws + OFF_WCTX + row*32;
      #pragma unroll
      for (int d2=0; d2<32; d2+=4){
        float4 w4 = *(const float4*)(wr+d2);
        g0 += w4.x*ctxl[bb*33+d2] + w4.y*ctxl[bb*33+d2+1]
            + w4.z*ctxl[bb*33+d2+2] + w4.w*ctxl[bb*33+d2+3];
      }
      gl[r*9+bb] = g0;
    }
    __syncthreads();
    if (tid < 64){
      int kk = tid>>3, bb = tid&7;
      float gi = gl[(kk)*9+bb],     gf = gl[(8+kk)*9+bb];
      float gg2 = gl[(16+kk)*9+bb], go = gl[(24+kk)*9+bb];
      float cp2 = c1l[tid];
      float cn = fsig(gf)*cp2 + fsig(gi)*ftanh(gg2);
      float hn = fsig(go)*ftanh(cn);
      c1l[tid] = cn;
      stc1(out + O_H1S + t*16384 + bg*4096 + (rg*8+kk)*8 + bb, hn);
      if (t == 63){
        int bgl = bg*8+bb, kgl = rg*8+kk;
        __builtin_nontemporal_store(hn, out + OUT_HF + bgl*512 + kgl);
        __builtin_nontemporal_store(cn, out + OUT_CF + bgl*512 + kgl);
      }
    }
    __syncthreads();
    if (tid == 0) flag_store(ws, C_H1, rg, tgt);

    // ================= P4: gates1 + cell2 (+ pg0(t+1)) =================
    waitA(ws, C_H1, tgt, tid);
    {
      const float* h1b = out + O_H1S + t*16384 + bg*4096;
      #pragma unroll
      for (int c=0;c<2;c++){
        int i = c*512 + tid;
        float4 v = *(const float4*)(h1b + i*4);
        int k = i>>1, bb0 = (i&1)*4;
        hs1[(bb0+0)*512+k]=v.x; hs1[(bb0+1)*512+k]=v.y;
        hs1[(bb0+2)*512+k]=v.z; hs1[(bb0+3)*512+k]=v.w;
      }
    }
    __syncthreads();
    // gates1 = wih1 @ h1 + whh1 @ h2(t-1): ONE pass, 4 rows x 8 b per wave
    {
      float vals[32];
      #pragma unroll
      for (int i=0;i<32;i++) vals[i] = 0.f;
      #pragma unroll
      for (int j=0;j<8;j++){
        int k = j*64 + L;
        float h1v[8], h2v[8];
        #pragma unroll
        for (int x=0;x<8;x++){ h1v[x] = hs1[x*512+k]; h2v[x] = hs2[x*512+k]; }
        #pragma unroll
        for (int r=0;r<4;r++){
          const float wa = w_a[r][j], wb = w_b[r][j];
          #pragma unroll
          for (int x=0;x<8;x++) vals[r*8+x] += wa*h1v[x] + wb*h2v[x];
        }
      }
      float v0 = redux32(vals, L);
      if (L < 32) gl[glIdx] = v0 + bsum;
    }
    __syncthreads();
    if (tid < 64){
      int kk = tid>>3, bb = tid&7;
      float gi = gl[(kk)*9+bb],     gf = gl[(8+kk)*9+bb];
      float gg2 = gl[(16+kk)*9+bb], go = gl[(24+kk)*9+bb];
      float cp3 = c2l[tid];
      float cn = fsig(gf)*cp3 + fsig(gi)*ftanh(gg2);
      float hn = fsig(go)*ftanh(cn);
      c2l[tid] = cn;
      int k2 = rg*8+kk, b = bg*8+bb;
      stc1(out + O_H2S + (t+1)*16384 + bg*4096 + k2*8 + bb, hn);
      __builtin_nontemporal_store(f2bf(hn), hbf + (t*32+b)*512 + k2);
      if (t == 63){
        __builtin_nontemporal_store(hn, out + OUT_HF + 16384 + b*512 + k2);
        __builtin_nontemporal_store(cn, out + OUT_CF + 16384 + b*512 + k2);
      }
    }
    __syncthreads();
    if (tid == 0) flag_store(ws, C_H2, rg, tgt);

    // pg0(t+1) = whh0 @ h1 (+ E0[t+1]) — ONE pass, 4 rows x 8 b per wave
    if (t < 63){
      {
        float vals[32];
        #pragma unroll
        for (int i=0;i<32;i++) vals[i] = 0.f;
        #pragma unroll
        for (int j=0;j<8;j++){
          int k = j*64 + L;
          float h1v[8];
          #pragma unroll
          for (int x=0;x<8;x++) h1v[x] = hs1[x*512+k];
          #pragma unroll
          for (int r=0;r<4;r++){
            const float wc = w0l[(W*4 + r)*512 + k];
            #pragma unroll
            for (int x=0;x<8;x++) vals[r*8+x] += wc*h1v[x];
          }
        }
        float v0 = redux32(vals, L);
        if (L < 32) pg0l[pgIdx] = v0;
      }
      __syncthreads();
      if (tid < 256){
        int r = tid>>3, bb = tid&7;
        int row = ((r>>3)<<9) + rg*8 + (r&7);
        pg0l[r*8+bb] += __builtin_nontemporal_load(
            ws + OFF_E0 + (t+1)*65536 + bg*16384 + row*8 + bb);
      }
    }
    // loop-top waitA's __syncthreads orders pg0l for next P3
  }
}

// ---------------- FC: logits = h @ fc_w^T + fc_b (bf16 MFMA) ----------------
__global__ __launch_bounds__(256) void fc_gemm(
    const float* __restrict__ ws_f, const float* __restrict__ fcb,
    float* __restrict__ out)
{
  const u16* A  = (const u16*)(ws_f + OFF_FCWBF);
  const u16* Bm = (const u16*)(ws_f + OFF_HBF);
  __shared__ u16 Al[128*40];
  __shared__ u16 Bl[128*40];
  int tid = threadIdx.x;
  int v0 = blockIdx.x*128, bt0 = blockIdx.y*128;
  int lane = tid & 63, wv = tid >> 6;
  int wr = wv >> 1, wc = wv & 1;
  f32x4 acc[4][4];
  #pragma unroll
  for (int i=0;i<4;i++)
    #pragma unroll
    for (int j=0;j<4;j++) acc[i][j] = (f32x4){0.f,0.f,0.f,0.f};

  int ar = wr*64 + (lane&15);
  int br = wc*64 + (lane&15);
  int ks = (lane>>4)*8;

  for (int kk=0; kk<512; kk+=32){
    __syncthreads();
    #pragma unroll
    for (int i=0;i<2;i++){
      int ld = tid + 256*i;
      int row = ld >> 2, cs = (ld & 3)*8;
      *(int4*)(&Al[row*40+cs]) = *(const int4*)(A  + (v0+row)*512 + kk + cs);
      *(int4*)(&Bl[row*40+cs]) = *(const int4*)(Bm + (bt0+row)*512 + kk + cs);
    }
    __syncthreads();
    short8 af[4], bf[4];
    #pragma unroll
    for (int m=0;m<4;m++) af[m] = *(const short8*)(&Al[(ar+m*16)*40 + ks]);
    #pragma unroll
    for (int n=0;n<4;n++) bf[n] = *(const short8*)(&Bl[(br+n*16)*40 + ks]);
    #pragma unroll
    for (int m=0;m<4;m++)
      #pragma unroll
      for (int n=0;n<4;n++)
        acc[m][n] = __builtin_amdgcn_mfma_f32_16x16x32_bf16(af[m], bf[n], acc[m][n], 0,0,0);
  }
  int r4 = (lane>>4)*4;
  #pragma unroll
  for (int m=0;m<4;m++){
    int v = v0 + wr*64 + m*16 + r4;
    float4 bias = *(const float4*)(fcb + v);
    #pragma unroll
    for (int n=0;n<4;n++){
      int bt = bt0 + wc*64 + n*16 + (lane&15);
      int b = bt & 31, t = bt >> 5;
      f32x4 a = acc[m][n];
      float4 res = { a[0]+bias.x, a[1]+bias.y, a[2]+bias.z, a[3]+bias.w };
      *(float4*)(out + b*2048000 + t*32000 + v) = res;
    }
  }
}

extern "C" void kernel_launch(void* const* d_in, const int* in_sizes, int n_in,
                              void* d_out, int out_size, void* d_ws, size_t ws_size,
                              hipStream_t stream)
{
  const int*   seq  = (const int*)d_in[0];
  const float* midi = (const float*)d_in[1];
  const float* emb  = (const float*)d_in[2];
  const float* mpw  = (const float*)d_in[3];
  const float* mpb  = (const float*)d_in[4];
  const float* wh   = (const float*)d_in[5];
  const float* wm   = (const float*)d_in[6];
  const float* vv   = (const float*)d_in[7];
  const float* wih0 = (const float*)d_in[8];
  const float* whh0 = (const float*)d_in[9];
  const float* bih0 = (const float*)d_in[10];
  const float* bhh0 = (const float*)d_in[11];
  const float* wih1 = (const float*)d_in[12];
  const float* whh1 = (const float*)d_in[13];
  const float* bih1 = (const float*)d_in[14];
  const float* bhh1 = (const float*)d_in[15];
  const float* fcw  = (const float*)d_in[16];
  const float* fcb  = (const float*)d_in[17];
  float* out = (float*)d_out;
  float* ws  = (float*)d_ws;

  hipFuncSetAttribute((const void*)scan_all,
                      hipFuncAttributeMaxDynamicSharedMemorySize,
                      SCAN_LDS_BYTES);

  p1_midi<<<32, 1024, 0, stream>>>(midi, mpw, mpb, wm, ws);
  p2a_x  <<<640, 256, 0, stream>>>(seq, emb, ws);
  p2b_w  <<<640, 256, 0, stream>>>(wih0, ws);
  p2c_e0 <<<dim3(16,16), 256, 0, stream>>>(ws, bih0, bhh0, ws);
  p3_cvt <<<8000, 256, 0, stream>>>(fcw, ws);
  p5_wctx<<<256, 256, 0, stream>>>(wih0, ws);
  p6_vc  <<<1, 512, 0, stream>>>(vv, ws);
  p0_init<<<64, 256, 0, stream>>>(ws, out);

  scan_all<<<NWG, 512, SCAN_LDS_BYTES, stream>>>(wih1, whh1, whh0, bih1, bhh1,
                                                 wh, vv, ws, out);

  fc_gemm<<<dim3(250,16), 256, 0, stream>>>(ws, fcb, out);
}